// Round 1
// baseline (2090.195 us; speedup 1.0000x reference)
//
#include <hip/hip_runtime.h>

// ---------------------------------------------------------------------------
// MultiHeadAttention_50646254354439 — deformable-attention-like module
// fp32 correctness baseline (R1). All GEMMs: simple 128x128x8 LDS-tiled fp32.
//
// Dims: B=1024, S=10, D=1024, E=1024, V=KD=128, H=M=8, K=3, HI=WI=16, BNM=32
// N = B*S = 10240
// ---------------------------------------------------------------------------

// ---------- generic fp32 GEMM: C[r][c] = sum_k A[r][k]*B[k][c] --------------
// A (Mr x Kd) row-major lda=Kd ; B (Kd x Nc) row-major (+ head stride) ;
// C (Mr x Nc) row-major (+ head stride). Mr = gridDim.x*128, Nc = gridDim.y*128.
__global__ __launch_bounds__(256) void sgemm128(
    const float* __restrict__ A, const float* __restrict__ Bw, float* __restrict__ C,
    int Kd, int Nc, long wStride, long cStride)
{
  __shared__ __align__(16) float As[8][128];
  __shared__ __align__(16) float Bs[8][128];
  const float* Bh = Bw + (long)blockIdx.z * wStride;
  float* Ch = C + (long)blockIdx.z * cStride;
  const int row0 = blockIdx.x * 128;
  const int col0 = blockIdx.y * 128;
  const int tid = threadIdx.x;
  const int tx = tid & 15, ty = tid >> 4;
  const int arow = tid >> 1, aseg = tid & 1;   // A stage: 128 rows x 2 float4
  const int bk = tid >> 5, bseg = tid & 31;    // B stage: 8 rows x 32 float4

  float acc[8][8];
#pragma unroll
  for (int i = 0; i < 8; ++i)
#pragma unroll
    for (int j = 0; j < 8; ++j) acc[i][j] = 0.f;

  const float* aptr = A + (long)(row0 + arow) * Kd + aseg * 4;
  const float* bptr = Bh + (long)bk * Nc + col0 + bseg * 4;

  for (int k0 = 0; k0 < Kd; k0 += 8) {
    float4 av = *(const float4*)(aptr + k0);
    float4 bv = *(const float4*)(bptr + (long)k0 * Nc);
    __syncthreads();
    As[aseg * 4 + 0][arow] = av.x;
    As[aseg * 4 + 1][arow] = av.y;
    As[aseg * 4 + 2][arow] = av.z;
    As[aseg * 4 + 3][arow] = av.w;
    *(float4*)&Bs[bk][bseg * 4] = bv;
    __syncthreads();
#pragma unroll
    for (int kk = 0; kk < 8; ++kk) {
      float a[8], bb[8];
      *(float4*)&a[0] = *(const float4*)&As[kk][ty * 8];
      *(float4*)&a[4] = *(const float4*)&As[kk][ty * 8 + 4];
      *(float4*)&bb[0] = *(const float4*)&Bs[kk][tx * 8];
      *(float4*)&bb[4] = *(const float4*)&Bs[kk][tx * 8 + 4];
#pragma unroll
      for (int i = 0; i < 8; ++i)
#pragma unroll
        for (int j = 0; j < 8; ++j)
          acc[i][j] = fmaf(a[i], bb[j], acc[i][j]);
    }
  }
#pragma unroll
  for (int i = 0; i < 8; ++i) {
    float* cp = Ch + (long)(row0 + ty * 8 + i) * Nc + col0 + tx * 8;
    *(float4*)cp = *(float4*)&acc[i][0];
    *(float4*)(cp + 4) = *(float4*)&acc[i][4];
  }
}

// ---------- Wq permutation: WqP[d][k*8+h] = Wq[h][d][k] ---------------------
// So that q2 = hf @ WqP lands directly in the reference's q2 flat layout:
// q2_flat[((b*10+s)*128+k)*8+h] = qp[h][b,s][k]  (row n=b*10+s, col k*8+h).
__global__ void wperm_kernel(const float* __restrict__ Wq, float* __restrict__ WqP)
{
  int i = blockIdx.x * 256 + threadIdx.x;
  if (i >= 1024 * 1024) return;
  int c = i & 1023, d = i >> 10;
  int k = c >> 3, h = c & 7;
  WqP[i] = Wq[((long)h * 1024 + d) * 128 + k];
}

// ---------- deltas: D[r][t] = q2row[r] . dw[t] + db[t], r<8192, t<60 --------
__global__ __launch_bounds__(64) void delta_kernel(
    const float* __restrict__ q2, const float* __restrict__ dw,
    const float* __restrict__ db, float* __restrict__ deltas)
{
  __shared__ __align__(16) float qrow[1280];
  int r = blockIdx.x;
  const float4* qr = (const float4*)(q2 + (long)r * 1280);
  for (int i = threadIdx.x; i < 320; i += 64) ((float4*)qrow)[i] = qr[i];
  __syncthreads();
  int t = threadIdx.x;
  if (t < 60) {
    const float4* dr = (const float4*)(dw + (long)t * 1280);
    float acc = 0.f;
    for (int j = 0; j < 320; ++j) {
      float4 d = dr[j];
      float4 qv = ((const float4*)qrow)[j];
      acc += d.x * qv.x + d.y * qv.y + d.z * qv.z + d.w * qv.w;
    }
    deltas[(long)r * 60 + t] = acc + db[t];
  }
}

// ---------- coords: pd = ref + deltas ; L2-normalize over the hi axis -------
// group g = (bnm, wi, s, kk); 16 hi values per group (that's dim=1 of pd!)
__global__ void coords_kernel(const float* __restrict__ deltas,
                              float* __restrict__ vgx, float* __restrict__ vgy)
{
  int g = blockIdx.x * 256 + threadIdx.x;
  if (g >= 32 * 16 * 10 * 3) return;
  int kk = g % 3, tmp = g / 3;
  int s = tmp % 10; tmp /= 10;
  int wi = tmp % 16; int bnm = tmp / 16;
  float gxr = wi * (1.0f / 15.0f);
  float px[16], py[16];
  float sx = 0.f, sy = 0.f;
#pragma unroll
  for (int hi = 0; hi < 16; ++hi) {
    long base = ((long)((bnm * 16 + hi) * 16 + wi)) * 60 + (s * 3 + kk) * 2;
    float x = gxr + deltas[base];
    float y = hi * (1.0f / 15.0f) + deltas[base + 1];
    px[hi] = x; py[hi] = y;
    sx += x * x; sy += y * y;
  }
  float rx = 1.0f / fmaxf(sqrtf(sx), 1e-12f);
  float ry = 1.0f / fmaxf(sqrtf(sy), 1e-12f);
#pragma unroll
  for (int hi = 0; hi < 16; ++hi) {
    long o = ((long)((bnm * 16 + hi) * 16 + wi) * 10 + s) * 3 + kk;
    vgx[o] = px[hi] * rx;
    vgy[o] = py[hi] * ry;
  }
}

// ---------- fused: bilinear k-sample + qk + softmax + P@V -------------------
// one block per (m,b) pair; bid = m*1024+b = bnm*256 + hi*16 + wi
__global__ __launch_bounds__(256) void attn_kernel(
    const float* __restrict__ q2, const float* __restrict__ kp,
    const float* __restrict__ vpz, const float* __restrict__ vgx,
    const float* __restrict__ vgy, float* __restrict__ head_flat,
    float* __restrict__ attn0)
{
  int bid = blockIdx.x;
  int m = bid >> 10, b = bid & 1023;
  int bnm = bid >> 8;
  int tid = threadIdx.x;

  __shared__ __align__(16) float qs[1280];
  __shared__ __align__(16) float ks[3840];
  __shared__ __align__(16) float vs[3840];
  __shared__ float qks[10][32];
  __shared__ float wst[30][4];
  __shared__ int cst[30][4];

  // 1. stage q rows (q_attn[m][b][s][v] = q2_flat[bid*1280 + s*128 + v])
  const float4* qsrc = (const float4*)(q2 + (long)bid * 1280);
  for (int i = tid; i < 320; i += 256) ((float4*)qs)[i] = qsrc[i];

  // 2. per-sample bilinear coefficients (t = kk*10 + sk)
  if (tid < 30) {
    int t = tid, kk = t / 10, sk = t % 10;
    long ci = ((long)bid * 10 + sk) * 3 + kk;
    float gx = vgx[ci], gy = vgy[ci];
    float ix = (gx + 1.0f) * 8.0f - 0.5f;   // ((gx+1)*16 - 1)*0.5
    float iy = (gy + 1.0f) * 8.0f - 0.5f;
    float x0f = floorf(ix), y0f = floorf(iy);
    float wx1 = ix - x0f, wx0 = 1.0f - wx1;
    float wy1 = iy - y0f, wy0 = 1.0f - wy1;
    float x1f = x0f + 1.0f, y1f = y0f + 1.0f;
    bool vx0 = (x0f >= 0.f) && (x0f <= 15.f);
    bool vx1 = (x1f >= 0.f) && (x1f <= 15.f);
    bool vy0 = (y0f >= 0.f) && (y0f <= 15.f);
    bool vy1 = (y1f >= 0.f) && (y1f <= 15.f);
    int x0 = min(max((int)x0f, 0), 15);
    int x1 = min(max((int)x1f, 0), 15);
    int y0 = min(max((int)y0f, 0), 15);
    int y1 = min(max((int)y1f, 0), 15);
    wst[t][0] = wx0 * wy0 * ((vx0 && vy0) ? 1.f : 0.f);
    wst[t][1] = wx1 * wy0 * ((vx1 && vy0) ? 1.f : 0.f);
    wst[t][2] = wx0 * wy1 * ((vx0 && vy1) ? 1.f : 0.f);
    wst[t][3] = wx1 * wy1 * ((vx1 && vy1) ? 1.f : 0.f);
    cst[t][0] = x0; cst[t][1] = x1; cst[t][2] = y0; cst[t][3] = y1;
  }

  // 3. stage V: vp[m][b][t][v] = vpz[(m*10240 + b*10 + t/3)*384 + (t%3)*128 + v]
  {
    long vbase = (long)m * 10240 + (long)b * 10;
    for (int i = tid; i < 960; i += 256) {
      int t = i >> 5;
      int off = (i & 31) * 4;
      int sv = t / 3, cv = t % 3;
      ((float4*)vs)[i] = *(const float4*)&vpz[(vbase + sv) * 384 + cv * 128 + off];
    }
  }
  __syncthreads();

  // 4. bilinear-sample K rows from kp (feats)
  {
    int pixbase = bnm << 8;
    for (int i = tid; i < 960; i += 256) {
      int t = i >> 5;
      int off = (i & 31) * 4;
      int sk = t % 10;
      int x0 = cst[t][0], x1 = cst[t][1], y0 = cst[t][2], y1 = cst[t][3];
      float w00 = wst[t][0], w10 = wst[t][1], w01 = wst[t][2], w11 = wst[t][3];
      const float4 f00 = *(const float4*)&kp[((long)(pixbase + y0 * 16 + x0) * 10 + sk) * 128 + off];
      const float4 f10 = *(const float4*)&kp[((long)(pixbase + y0 * 16 + x1) * 10 + sk) * 128 + off];
      const float4 f01 = *(const float4*)&kp[((long)(pixbase + y1 * 16 + x0) * 10 + sk) * 128 + off];
      const float4 f11 = *(const float4*)&kp[((long)(pixbase + y1 * 16 + x1) * 10 + sk) * 128 + off];
      float4 acc;
      acc.x = w00 * f00.x + w10 * f10.x + w01 * f01.x + w11 * f11.x;
      acc.y = w00 * f00.y + w10 * f10.y + w01 * f01.y + w11 * f11.y;
      acc.z = w00 * f00.z + w10 * f10.z + w01 * f01.z + w11 * f11.z;
      acc.w = w00 * f00.w + w10 * f10.w + w01 * f01.w + w11 * f11.w;
      ((float4*)ks)[i] = acc;
    }
  }
  __syncthreads();

  // 5. qk[s][t] = (q_s . k_t) / sqrt(128)
  for (int e = tid; e < 300; e += 256) {
    int s = e / 30, t = e % 30;
    const float4* qv = (const float4*)&qs[s * 128];
    const float4* kv = (const float4*)&ks[t * 128];
    float acc = 0.f;
#pragma unroll
    for (int j = 0; j < 32; ++j) {
      float4 a = qv[j], c = kv[j];
      acc += a.x * c.x + a.y * c.y + a.z * c.z + a.w * c.w;
    }
    qks[s][t] = acc * 0.08838834764831845f;
  }
  __syncthreads();

  // 6. softmax over t (rows of 30)
  if (tid < 10) {
    int s = tid;
    float mx = -1e30f;
    for (int t = 0; t < 30; ++t) mx = fmaxf(mx, qks[s][t]);
    float sum = 0.f;
    for (int t = 0; t < 30; ++t) {
      float e = __expf(qks[s][t] - mx);
      qks[s][t] = e; sum += e;
    }
    float inv = 1.0f / sum;
    for (int t = 0; t < 30; ++t) qks[s][t] *= inv;
  }
  __syncthreads();
  if (tid < 30) attn0[(long)bid * 30 + tid] = qks[0][tid];

  // 7. head[s][v] = sum_t attn[s][t] * vs[t][v] ; store to head_flat
  for (int i = tid; i < 320; i += 256) {
    int s = i >> 5;
    int off = (i & 31) * 4;
    float4 acc = {0.f, 0.f, 0.f, 0.f};
    for (int t = 0; t < 30; ++t) {
      float a = qks[s][t];
      const float4 v = *(const float4*)&vs[t * 128 + off];
      acc.x += a * v.x; acc.y += a * v.y; acc.z += a * v.z; acc.w += a * v.w;
    }
    *(float4*)&head_flat[((long)(b * 10 + s)) * 1024 + m * 128 + off] = acc;
  }
}

// ---------- attn_map[b][t] = mean_m attn0[m][b][t] --------------------------
__global__ void attnmap_kernel(const float* __restrict__ attn0, float* __restrict__ outa)
{
  int i = blockIdx.x * 256 + threadIdx.x;
  if (i >= 30720) return;
  int b = i / 30, t = i % 30;
  float s = 0.f;
  for (int mm = 0; mm < 8; ++mm) s += attn0[((long)mm * 1024 + b) * 30 + t];
  outa[i] = 0.125f * s;
}

// ---------------------------------------------------------------------------
extern "C" void kernel_launch(void* const* d_in, const int* in_sizes, int n_in,
                              void* d_out, int out_size, void* d_ws, size_t ws_size,
                              hipStream_t stream)
{
  const float* q  = (const float*)d_in[0];
  const float* Wq = (const float*)d_in[1];
  const float* Wk = (const float*)d_in[2];
  const float* Wv = (const float*)d_in[3];
  const float* Wo = (const float*)d_in[4];
  const float* dw = (const float*)d_in[5];
  const float* db = (const float*)d_in[6];
  float* out = (float*)d_out;
  float* attn_out = out + 10485760;  // out (10,485,760) then attn_map (30,720)
  float* ws = (float*)d_ws;

  // workspace layout (floats); total 65,191,936 fl = 260.8 MB
  float* WqP   = ws;                  // 1,048,576
  float* q2    = WqP + 1048576;       // 10,485,760
  float* kp    = q2 + 10485760;       // 10,485,760
  float* vpz   = kp + 10485760;       // 31,457,280
  float* dels  = vpz + 31457280;      // 491,520
  float* vgx   = dels + 491520;       // 245,760
  float* vgy   = vgx + 245760;        // 245,760
  float* attn0 = vgy + 245760;        // 245,760
  float* headf = attn0 + 245760;      // 10,485,760

  // 1. permute Wq so q2 = hf @ WqP directly in reference flat layout
  wperm_kernel<<<dim3(4096), dim3(256), 0, stream>>>(Wq, WqP);
  // 2. q2 (10240x1024 = hf @ WqP)
  sgemm128<<<dim3(80, 8, 1), dim3(256), 0, stream>>>(q, WqP, q2, 1024, 1024, 0L, 0L);
  // 3. kp[h] = hf @ Wk[h]  (8 heads, 10240x128)
  sgemm128<<<dim3(80, 1, 8), dim3(256), 0, stream>>>(q, Wk, kp, 1024, 128,
                                                     (long)1024 * 128, (long)10240 * 128);
  // 4. vpz[h] = hf @ Wv[h] (8 heads, 10240x384)
  sgemm128<<<dim3(80, 3, 8), dim3(256), 0, stream>>>(q, Wv, vpz, 1024, 384,
                                                     (long)1024 * 384, (long)10240 * 384);
  // 5. deltas = q2 @ dw^T + db   (8192 x 60)
  delta_kernel<<<dim3(8192), dim3(64), 0, stream>>>(q2, dw, db, dels);
  // 6. reference-point add + L2 normalize over hi axis
  coords_kernel<<<dim3(60), dim3(256), 0, stream>>>(dels, vgx, vgy);
  // 7. fused sample + attention per (m,b)
  attn_kernel<<<dim3(8192), dim3(256), 0, stream>>>(q2, kp, vpz, vgx, vgy, headf, attn0);
  // 8. attn_map = mean over heads of attn[:, :, 0, :]
  attnmap_kernel<<<dim3(120), dim3(256), 0, stream>>>(attn0, attn_out);
  // 9. out = head_flat @ Wo_flat (1024x1024)
  sgemm128<<<dim3(80, 8, 1), dim3(256), 0, stream>>>(headf, Wo, out, 1024, 1024, 0L, 0L);
}

// Round 2
// 689.547 us; speedup vs baseline: 3.0313x; 3.0313x over previous
//
#include <hip/hip_runtime.h>

// ---------------------------------------------------------------------------
// MultiHeadAttention_50646254354439 — R2: bf16 MFMA GEMM stack (m97 structure)
// Dims: B=1024, S=10, D=1024, E=1024, V=KD=128, H=M=8, K=3, HI=WI=16
// N = B*S = 10240
// ---------------------------------------------------------------------------

typedef float    f32x4 __attribute__((ext_vector_type(4)));
typedef short    s16x8 __attribute__((ext_vector_type(8)));
typedef unsigned short u16x8 __attribute__((ext_vector_type(8)));
typedef unsigned short u16x4 __attribute__((ext_vector_type(4)));
typedef unsigned short u16;

__device__ __forceinline__ u16 f2bf(float f) {   // RNE float->bf16
  union { float f; unsigned u; } x; x.f = f;
  unsigned r = x.u + 0x7FFFu + ((x.u >> 16) & 1u);
  return (u16)(r >> 16);
}
__device__ __forceinline__ float bf2f(u16 u) {
  union { unsigned u; float f; } x; x.u = ((unsigned)u) << 16;
  return x.f;
}

#define ASYNC16(g, l) __builtin_amdgcn_global_load_lds(                       \
    (const __attribute__((address_space(1))) void*)(g),                       \
    (__attribute__((address_space(3))) void*)(l), 16, 0, 0)

// ---------- fp32 -> bf16 elementwise (A matrix: q, row-major [10240][1024]) -
__global__ __launch_bounds__(256) void conv_a(
    const float* __restrict__ src, u16* __restrict__ dst, int n8)
{
  int i = blockIdx.x * 256 + threadIdx.x;
  if (i >= n8) return;
  const float4* s = (const float4*)src + (size_t)i * 2;
  float4 a = s[0], b = s[1];
  u16x8 o;
  o[0] = f2bf(a.x); o[1] = f2bf(a.y); o[2] = f2bf(a.z); o[3] = f2bf(a.w);
  o[4] = f2bf(b.x); o[5] = f2bf(b.y); o[6] = f2bf(b.z); o[7] = f2bf(b.w);
  *(u16x8*)(dst + (size_t)i * 8) = o;
}

// ---------- build fused B^T (K-contiguous) weight matrix, bf16 --------------
// WcatT rows (each row = one output column, 1024 k-elements contiguous):
//   [0,1024):    q2 col c=kq*8+h     <- Wq[h][d][kq]
//   [1024,2048): kp col h*128+k      <- Wk[h][d][k]
//   [2048,5120): vp col h*384+cc     <- Wv[h][d][cc]
//   [5120,6144): out col e           <- WoFlat[j][e] = Wo[j*1024+e]
__global__ __launch_bounds__(256) void conv_w(
    const float* __restrict__ Wq, const float* __restrict__ Wk,
    const float* __restrict__ Wv, const float* __restrict__ Wo,
    u16* __restrict__ Wcat)
{
  int i = blockIdx.x * 256 + threadIdx.x;   // 6144*128 = 786432 threads
  if (i >= 6144 * 128) return;
  int c = i >> 7;
  int d0 = (i & 127) * 8;
  const float* src; int stride;
  if (c < 1024)      { int kq = c >> 3, h = c & 7;
                       src = Wq + (size_t)h * 131072 + kq;      stride = 128; }
  else if (c < 2048) { int j = c - 1024; int h = j >> 7, k = j & 127;
                       src = Wk + (size_t)h * 131072 + k;       stride = 128; }
  else if (c < 5120) { int j = c - 2048; int h = j / 384, cc = j - h * 384;
                       src = Wv + (size_t)h * 393216 + cc;      stride = 384; }
  else               { int e = c - 5120;
                       src = Wo + e;                            stride = 1024; }
  u16x8 o;
#pragma unroll
  for (int r = 0; r < 8; ++r) o[r] = f2bf(src[(size_t)(d0 + r) * stride]);
  *(u16x8*)(Wcat + (size_t)c * 1024 + d0) = o;
}

// ---------- bf16 MFMA GEMM (m97 structure): C = A @ Bt^T --------------------
// A  bf16 [Mrows][1024] row-major; Bt bf16 [Ncols][1024] row-major (B^T).
// C fp32 or bf16, [Mrows][ldc]. Tile 128x128, BK=32, 4 waves of 64x64.
template<int OUTBF>
__global__ __launch_bounds__(256) void gemm_mfma(
    const u16* __restrict__ A, const u16* __restrict__ Bt,
    void* __restrict__ Cv, int ldc)
{
  __shared__ __align__(16) u16 As[128 * 32];
  __shared__ __align__(16) u16 Bs[128 * 32];
  const int tid  = threadIdx.x;
  const int lane = tid & 63;
  const int w    = tid >> 6;
  const int row0 = blockIdx.x * 128;
  const int col0 = blockIdx.y * 128;
  const int wr   = (w >> 1) * 64;
  const int wc   = (w & 1) * 64;
  const int lrow = lane & 15;
  const int lk   = lane >> 4;     // 0..3 -> k-offset lk*8

  f32x4 acc[4][4];
#pragma unroll
  for (int i = 0; i < 4; ++i)
#pragma unroll
    for (int j = 0; j < 4; ++j) acc[i][j] = (f32x4){0.f, 0.f, 0.f, 0.f};

  // staging: tile = 128 rows x 32 bf16 = 512 chunks of 16B; 2 issues/matrix
  const int c0 = tid, c1 = 256 + tid;
  const int ar0 = c0 >> 2, aj0 = c0 & 3;
  const int ar1 = c1 >> 2, aj1 = c1 & 3;
  const u16* Ag0 = A  + (size_t)(row0 + ar0) * 1024 + aj0 * 8;
  const u16* Ag1 = A  + (size_t)(row0 + ar1) * 1024 + aj1 * 8;
  const u16* Bg0 = Bt + (size_t)(col0 + ar0) * 1024 + aj0 * 8;
  const u16* Bg1 = Bt + (size_t)(col0 + ar1) * 1024 + aj1 * 8;
  char* AsB = (char*)As;  char* BsB = (char*)Bs;
  char* aL0 = AsB + w * 1024;         char* aL1 = AsB + 4096 + w * 1024;
  char* bL0 = BsB + w * 1024;         char* bL1 = BsB + 4096 + w * 1024;

  // fragment LDS byte offsets (constant across K loop)
  int aoff[4], boff[4];
#pragma unroll
  for (int f = 0; f < 4; ++f) {
    aoff[f] = (wr + f * 16 + lrow) * 64 + lk * 16;
    boff[f] = (wc + f * 16 + lrow) * 64 + lk * 16;
  }

  for (int k0 = 0; k0 < 1024; k0 += 32) {
    if (k0) __syncthreads();
    ASYNC16(Ag0 + k0, aL0);
    ASYNC16(Ag1 + k0, aL1);
    ASYNC16(Bg0 + k0, bL0);
    ASYNC16(Bg1 + k0, bL1);
    asm volatile("s_waitcnt vmcnt(0)" ::: "memory");
    __syncthreads();

    s16x8 af[4], bf[4];
#pragma unroll
    for (int f = 0; f < 4; ++f) af[f] = *(const s16x8*)(AsB + aoff[f]);
#pragma unroll
    for (int f = 0; f < 4; ++f) bf[f] = *(const s16x8*)(BsB + boff[f]);
#pragma unroll
    for (int fm = 0; fm < 4; ++fm)
#pragma unroll
      for (int fn = 0; fn < 4; ++fn)
        acc[fm][fn] = __builtin_amdgcn_mfma_f32_16x16x32_bf16(
            af[fm], bf[fn], acc[fm][fn], 0, 0, 0);
  }

  // epilogue: C/D layout col=lane&15, row=(lane>>4)*4+reg  [m89-verified]
  const int crow = lane >> 4;
  const int ccol = lane & 15;
#pragma unroll
  for (int fm = 0; fm < 4; ++fm)
#pragma unroll
    for (int fn = 0; fn < 4; ++fn) {
      size_t rb = (size_t)(row0 + wr + fm * 16 + crow * 4);
      int col = col0 + wc + fn * 16 + ccol;
      if (OUTBF) {
        u16* C = (u16*)Cv;
#pragma unroll
        for (int r = 0; r < 4; ++r)
          C[(rb + r) * ldc + col] = f2bf(acc[fm][fn][r]);
      } else {
        float* C = (float*)Cv;
#pragma unroll
        for (int r = 0; r < 4; ++r)
          C[(rb + r) * ldc + col] = acc[fm][fn][r];
      }
    }
}

// ---------- deltas: D[r][t] = q2row[r] . dw[t] + db[t], r<8192, t<60 --------
__global__ __launch_bounds__(64) void delta_kernel(
    const float* __restrict__ q2, const float* __restrict__ dw,
    const float* __restrict__ db, float* __restrict__ deltas)
{
  __shared__ __align__(16) float qrow[1280];
  int r = blockIdx.x;
  const float4* qr = (const float4*)(q2 + (size_t)r * 1280);
  for (int i = threadIdx.x; i < 320; i += 64) ((float4*)qrow)[i] = qr[i];
  __syncthreads();
  int t = threadIdx.x;
  if (t < 60) {
    const float4* dr = (const float4*)(dw + (size_t)t * 1280);
    float acc = 0.f;
    for (int j = 0; j < 320; ++j) {
      float4 d = dr[j];
      float4 qv = ((const float4*)qrow)[j];
      acc += d.x * qv.x + d.y * qv.y + d.z * qv.z + d.w * qv.w;
    }
    deltas[(size_t)r * 60 + t] = acc + db[t];
  }
}

// ---------- coords: pd = ref + deltas ; L2-normalize over the hi axis -------
__global__ void coords_kernel(const float* __restrict__ deltas,
                              float* __restrict__ vgx, float* __restrict__ vgy)
{
  int g = blockIdx.x * 256 + threadIdx.x;
  if (g >= 32 * 16 * 10 * 3) return;
  int kk = g % 3, tmp = g / 3;
  int s = tmp % 10; tmp /= 10;
  int wi = tmp % 16; int bnm = tmp / 16;
  float gxr = wi * (1.0f / 15.0f);
  float px[16], py[16];
  float sx = 0.f, sy = 0.f;
#pragma unroll
  for (int hi = 0; hi < 16; ++hi) {
    size_t base = ((size_t)((bnm * 16 + hi) * 16 + wi)) * 60 + (s * 3 + kk) * 2;
    float x = gxr + deltas[base];
    float y = hi * (1.0f / 15.0f) + deltas[base + 1];
    px[hi] = x; py[hi] = y;
    sx += x * x; sy += y * y;
  }
  float rx = 1.0f / fmaxf(sqrtf(sx), 1e-12f);
  float ry = 1.0f / fmaxf(sqrtf(sy), 1e-12f);
#pragma unroll
  for (int hi = 0; hi < 16; ++hi) {
    size_t o = ((size_t)((bnm * 16 + hi) * 16 + wi) * 10 + s) * 3 + kk;
    vgx[o] = px[hi] * rx;
    vgy[o] = py[hi] * ry;
  }
}

// ---------- fused: bilinear k-sample + qk + softmax + P@V -------------------
// one block per (m,b); kp2 fp32 [n][1024] (col m*128+k), vp2 bf16 [n][3072]
__global__ __launch_bounds__(256) void attn_kernel(
    const float* __restrict__ q2, const float* __restrict__ kp2,
    const u16* __restrict__ vp2, const float* __restrict__ vgx,
    const float* __restrict__ vgy, u16* __restrict__ headf,
    float* __restrict__ attn0)
{
  int bid = blockIdx.x;
  int m = bid >> 10, b = bid & 1023;
  int tid = threadIdx.x;

  __shared__ __align__(16) float qs[1280];
  __shared__ __align__(16) float ks[3840];
  __shared__ __align__(16) float vs[3840];
  __shared__ float qks[10][32];
  __shared__ float wst[30][4];
  __shared__ int cst[30][4];

  // 1. stage q rows (q_attn[m][b][s][v] = q2_flat[bid*1280 + s*128 + v])
  const float4* qsrc = (const float4*)(q2 + (size_t)bid * 1280);
  for (int i = tid; i < 320; i += 256) ((float4*)qs)[i] = qsrc[i];

  // 2. per-sample bilinear coefficients (t = kk*10 + sk)
  if (tid < 30) {
    int t = tid, kk = t / 10, sk = t % 10;
    size_t ci = ((size_t)bid * 10 + sk) * 3 + kk;
    float gx = vgx[ci], gy = vgy[ci];
    float ix = (gx + 1.0f) * 8.0f - 0.5f;
    float iy = (gy + 1.0f) * 8.0f - 0.5f;
    float x0f = floorf(ix), y0f = floorf(iy);
    float wx1 = ix - x0f, wx0 = 1.0f - wx1;
    float wy1 = iy - y0f, wy0 = 1.0f - wy1;
    float x1f = x0f + 1.0f, y1f = y0f + 1.0f;
    bool vx0 = (x0f >= 0.f) && (x0f <= 15.f);
    bool vx1 = (x1f >= 0.f) && (x1f <= 15.f);
    bool vy0 = (y0f >= 0.f) && (y0f <= 15.f);
    bool vy1 = (y1f >= 0.f) && (y1f <= 15.f);
    int x0 = min(max((int)x0f, 0), 15);
    int x1 = min(max((int)x1f, 0), 15);
    int y0 = min(max((int)y0f, 0), 15);
    int y1 = min(max((int)y1f, 0), 15);
    wst[t][0] = wx0 * wy0 * ((vx0 && vy0) ? 1.f : 0.f);
    wst[t][1] = wx1 * wy0 * ((vx1 && vy0) ? 1.f : 0.f);
    wst[t][2] = wx0 * wy1 * ((vx0 && vy1) ? 1.f : 0.f);
    wst[t][3] = wx1 * wy1 * ((vx1 && vy1) ? 1.f : 0.f);
    cst[t][0] = x0; cst[t][1] = x1; cst[t][2] = y0; cst[t][3] = y1;
  }

  // 3. stage V (bf16 -> f32 LDS): vp[t] row b*10+t/3, col m*384+(t%3)*128
  for (int i = tid; i < 480; i += 256) {
    int t = i >> 4, off = (i & 15) * 8;
    int sv = t / 3, cv = t - sv * 3;
    u16x8 v = *(const u16x8*)(vp2 + ((size_t)(b * 10 + sv)) * 3072 +
                              m * 384 + cv * 128 + off);
    float* d = &vs[t * 128 + off];
#pragma unroll
    for (int r = 0; r < 8; ++r) d[r] = bf2f(v[r]);
  }
  __syncthreads();

  // 4. bilinear-sample K rows from kp2 (row n = (pb + y*16+x)*10 + sk)
  {
    int pb = (b >> 8) << 8;
    for (int i = tid; i < 960; i += 256) {
      int t = i >> 5, off = (i & 31) * 4;
      int sk = t % 10;
      int x0 = cst[t][0], x1 = cst[t][1], y0 = cst[t][2], y1 = cst[t][3];
      float w00 = wst[t][0], w10 = wst[t][1], w01 = wst[t][2], w11 = wst[t][3];
      size_t colo = (size_t)m * 128 + off;
      const float4 f00 = *(const float4*)&kp2[((size_t)((pb + y0 * 16 + x0) * 10 + sk)) * 1024 + colo];
      const float4 f10 = *(const float4*)&kp2[((size_t)((pb + y0 * 16 + x1) * 10 + sk)) * 1024 + colo];
      const float4 f01 = *(const float4*)&kp2[((size_t)((pb + y1 * 16 + x0) * 10 + sk)) * 1024 + colo];
      const float4 f11 = *(const float4*)&kp2[((size_t)((pb + y1 * 16 + x1) * 10 + sk)) * 1024 + colo];
      float4 acc;
      acc.x = w00 * f00.x + w10 * f10.x + w01 * f01.x + w11 * f11.x;
      acc.y = w00 * f00.y + w10 * f10.y + w01 * f01.y + w11 * f11.y;
      acc.z = w00 * f00.z + w10 * f10.z + w01 * f01.z + w11 * f11.z;
      acc.w = w00 * f00.w + w10 * f10.w + w01 * f01.w + w11 * f11.w;
      ((float4*)ks)[i] = acc;
    }
  }
  __syncthreads();

  // 5. qk[s][t] = (q_s . k_t) / sqrt(128)
  for (int e = tid; e < 300; e += 256) {
    int s = e / 30, t = e % 30;
    const float4* qv = (const float4*)&qs[s * 128];
    const float4* kv = (const float4*)&ks[t * 128];
    float acc = 0.f;
#pragma unroll
    for (int j = 0; j < 32; ++j) {
      float4 a = qv[j], c = kv[j];
      acc += a.x * c.x + a.y * c.y + a.z * c.z + a.w * c.w;
    }
    qks[s][t] = acc * 0.08838834764831845f;
  }
  __syncthreads();

  // 6. softmax over t
  if (tid < 10) {
    int s = tid;
    float mx = -1e30f;
    for (int t = 0; t < 30; ++t) mx = fmaxf(mx, qks[s][t]);
    float sum = 0.f;
    for (int t = 0; t < 30; ++t) {
      float e = __expf(qks[s][t] - mx);
      qks[s][t] = e; sum += e;
    }
    float inv = 1.0f / sum;
    for (int t = 0; t < 30; ++t) qks[s][t] *= inv;
  }
  __syncthreads();
  if (tid < 30) attn0[(size_t)bid * 30 + tid] = qks[0][tid];

  // 7. head[s][v] = sum_t attn[s][t] * vs[t][v] ; store bf16 to headf
  for (int i = tid; i < 320; i += 256) {
    int s = i >> 5, off = (i & 31) * 4;
    float4 acc = {0.f, 0.f, 0.f, 0.f};
    for (int t = 0; t < 30; ++t) {
      float a = qks[s][t];
      const float4 v = *(const float4*)&vs[t * 128 + off];
      acc.x += a * v.x; acc.y += a * v.y; acc.z += a * v.z; acc.w += a * v.w;
    }
    u16x4 o;
    o[0] = f2bf(acc.x); o[1] = f2bf(acc.y); o[2] = f2bf(acc.z); o[3] = f2bf(acc.w);
    *(u16x4*)&headf[((size_t)(b * 10 + s)) * 1024 + m * 128 + off] = o;
  }
}

// ---------- attn_map[b][t] = mean_m attn0[m][b][t] --------------------------
__global__ void attnmap_kernel(const float* __restrict__ attn0, float* __restrict__ outa)
{
  int i = blockIdx.x * 256 + threadIdx.x;
  if (i >= 30720) return;
  int b = i / 30, t = i % 30;
  float s = 0.f;
  for (int mm = 0; mm < 8; ++mm) s += attn0[((size_t)mm * 1024 + b) * 30 + t];
  outa[i] = 0.125f * s;
}

// ---------------------------------------------------------------------------
extern "C" void kernel_launch(void* const* d_in, const int* in_sizes, int n_in,
                              void* d_out, int out_size, void* d_ws, size_t ws_size,
                              hipStream_t stream)
{
  const float* q  = (const float*)d_in[0];
  const float* Wq = (const float*)d_in[1];
  const float* Wk = (const float*)d_in[2];
  const float* Wv = (const float*)d_in[3];
  const float* Wo = (const float*)d_in[4];
  const float* dw = (const float*)d_in[5];
  const float* db = (const float*)d_in[6];
  float* out = (float*)d_out;
  float* attn_out = out + 10485760;

  // workspace layout (bytes): total ~197 MB
  char* p = (char*)d_ws;
  u16*   Abf   = (u16*)p;   p += 20971520;   // [10240][1024] bf16
  u16*   Wcat  = (u16*)p;   p += 12582912;   // [6144][1024] bf16 (B^T fused)
  float* q2    = (float*)p; p += 41943040;   // [10240][1024] fp32
  float* kp2   = (float*)p; p += 41943040;   // [10240][1024] fp32
  u16*   vp2   = (u16*)p;   p += 62914560;   // [10240][3072] bf16
  u16*   headf = (u16*)p;   p += 20971520;   // [10240][1024] bf16
  float* dels  = (float*)p; p += 1966080;    // [8192][60]
  float* vgxp  = (float*)p; p += 983040;
  float* vgyp  = (float*)p; p += 983040;
  float* attn0 = (float*)p; p += 983040;

  conv_a<<<dim3(5120), dim3(256), 0, stream>>>(q, Abf, 1310720);
  conv_w<<<dim3(3072), dim3(256), 0, stream>>>(Wq, Wk, Wv, Wo, Wcat);

  // q2 (fp32), kp2 (fp32), vp2 (bf16) — all A = Abf, Bt = WcatT segments
  gemm_mfma<0><<<dim3(80, 8), dim3(256), 0, stream>>>(Abf, Wcat, q2, 1024);
  gemm_mfma<0><<<dim3(80, 8), dim3(256), 0, stream>>>(Abf, Wcat + (size_t)1024 * 1024, kp2, 1024);
  gemm_mfma<1><<<dim3(80, 24), dim3(256), 0, stream>>>(Abf, Wcat + (size_t)2048 * 1024, vp2, 3072);

  delta_kernel<<<dim3(8192), dim3(64), 0, stream>>>(q2, dw, db, dels);
  coords_kernel<<<dim3(60), dim3(256), 0, stream>>>(dels, vgxp, vgyp);
  attn_kernel<<<dim3(8192), dim3(256), 0, stream>>>(q2, kp2, vp2, vgxp, vgyp, headf, attn0);
  attnmap_kernel<<<dim3(120), dim3(256), 0, stream>>>(attn0, attn_out);

  // out = headf @ Wo  (A bf16, Bt rows 5120..6143)
  gemm_mfma<0><<<dim3(80, 8), dim3(256), 0, stream>>>(headf, Wcat + (size_t)5120 * 1024, out, 1024);
}

// Round 3
// 440.084 us; speedup vs baseline: 4.7495x; 1.5669x over previous
//
#include <hip/hip_runtime.h>

// ---------------------------------------------------------------------------
// MultiHeadAttention_50646254354439 — R3: delta GEMM -> MFMA; q2 dual-write
// Dims: B=1024, S=10, D=1024, E=1024, V=KD=128, H=M=8, K=3, HI=WI=16
// N = B*S = 10240
// ---------------------------------------------------------------------------

typedef float    f32x4 __attribute__((ext_vector_type(4)));
typedef short    s16x8 __attribute__((ext_vector_type(8)));
typedef unsigned short u16x8 __attribute__((ext_vector_type(8)));
typedef unsigned short u16x4 __attribute__((ext_vector_type(4)));
typedef unsigned short u16;

__device__ __forceinline__ u16 f2bf(float f) {   // RNE float->bf16
  union { float f; unsigned u; } x; x.f = f;
  unsigned r = x.u + 0x7FFFu + ((x.u >> 16) & 1u);
  return (u16)(r >> 16);
}
__device__ __forceinline__ float bf2f(u16 u) {
  union { unsigned u; float f; } x; x.u = ((unsigned)u) << 16;
  return x.f;
}

#define ASYNC16(g, l) __builtin_amdgcn_global_load_lds(                       \
    (const __attribute__((address_space(1))) void*)(g),                       \
    (__attribute__((address_space(3))) void*)(l), 16, 0, 0)

// ---------- fp32 -> bf16 elementwise (A matrix: q, row-major [10240][1024]) -
__global__ __launch_bounds__(256) void conv_a(
    const float* __restrict__ src, u16* __restrict__ dst, int n8)
{
  int i = blockIdx.x * 256 + threadIdx.x;
  if (i >= n8) return;
  const float4* s = (const float4*)src + (size_t)i * 2;
  float4 a = s[0], b = s[1];
  u16x8 o;
  o[0] = f2bf(a.x); o[1] = f2bf(a.y); o[2] = f2bf(a.z); o[3] = f2bf(a.w);
  o[4] = f2bf(b.x); o[5] = f2bf(b.y); o[6] = f2bf(b.z); o[7] = f2bf(b.w);
  *(u16x8*)(dst + (size_t)i * 8) = o;
}

// ---------- build fused B^T (K-contiguous) weight matrix, bf16 --------------
__global__ __launch_bounds__(256) void conv_w(
    const float* __restrict__ Wq, const float* __restrict__ Wk,
    const float* __restrict__ Wv, const float* __restrict__ Wo,
    u16* __restrict__ Wcat)
{
  int i = blockIdx.x * 256 + threadIdx.x;   // 6144*128 = 786432 threads
  if (i >= 6144 * 128) return;
  int c = i >> 7;
  int d0 = (i & 127) * 8;
  const float* src; int stride;
  if (c < 1024)      { int kq = c >> 3, h = c & 7;
                       src = Wq + (size_t)h * 131072 + kq;      stride = 128; }
  else if (c < 2048) { int j = c - 1024; int h = j >> 7, k = j & 127;
                       src = Wk + (size_t)h * 131072 + k;       stride = 128; }
  else if (c < 5120) { int j = c - 2048; int h = j / 384, cc = j - h * 384;
                       src = Wv + (size_t)h * 393216 + cc;      stride = 384; }
  else               { int e = c - 5120;
                       src = Wo + e;                            stride = 1024; }
  u16x8 o;
#pragma unroll
  for (int r = 0; r < 8; ++r) o[r] = f2bf(src[(size_t)(d0 + r) * stride]);
  *(u16x8*)(Wcat + (size_t)c * 1024 + d0) = o;
}

// ---------- dw -> bf16 [64][1280] (rows >=60 dummy=row0, never written) -----
__global__ __launch_bounds__(256) void conv_dw(
    const float* __restrict__ dw, u16* __restrict__ dwbf)
{
  int i = blockIdx.x * 256 + threadIdx.x;   // 64*160 = 10240 chunks
  if (i >= 10240) return;
  int row = i / 160, ch = i - row * 160;
  int srow = (row < 60) ? row : 0;
  const float4* s = (const float4*)(dw + (size_t)srow * 1280 + ch * 8);
  float4 a = s[0], b = s[1];
  u16x8 o;
  o[0] = f2bf(a.x); o[1] = f2bf(a.y); o[2] = f2bf(a.z); o[3] = f2bf(a.w);
  o[4] = f2bf(b.x); o[5] = f2bf(b.y); o[6] = f2bf(b.z); o[7] = f2bf(b.w);
  *(u16x8*)(dwbf + (size_t)row * 1280 + ch * 8) = o;
}

// ---------- bf16 MFMA GEMM (m97 structure): C = A @ Bt^T --------------------
// OUTMODE: 0 = fp32 C; 1 = bf16 C; 2 = fp32 C + bf16 Cbf (same ldc)
template<int OUTMODE>
__global__ __launch_bounds__(256) void gemm_mfma(
    const u16* __restrict__ A, const u16* __restrict__ Bt,
    void* __restrict__ Cv, u16* __restrict__ Cbf, int ldc)
{
  __shared__ __align__(16) u16 As[128 * 32];
  __shared__ __align__(16) u16 Bs[128 * 32];
  const int tid  = threadIdx.x;
  const int lane = tid & 63;
  const int w    = tid >> 6;
  const int row0 = blockIdx.x * 128;
  const int col0 = blockIdx.y * 128;
  const int wr   = (w >> 1) * 64;
  const int wc   = (w & 1) * 64;
  const int lrow = lane & 15;
  const int lk   = lane >> 4;

  f32x4 acc[4][4];
#pragma unroll
  for (int i = 0; i < 4; ++i)
#pragma unroll
    for (int j = 0; j < 4; ++j) acc[i][j] = (f32x4){0.f, 0.f, 0.f, 0.f};

  const int c0 = tid, c1 = 256 + tid;
  const int ar0 = c0 >> 2, aj0 = c0 & 3;
  const int ar1 = c1 >> 2, aj1 = c1 & 3;
  const u16* Ag0 = A  + (size_t)(row0 + ar0) * 1024 + aj0 * 8;
  const u16* Ag1 = A  + (size_t)(row0 + ar1) * 1024 + aj1 * 8;
  const u16* Bg0 = Bt + (size_t)(col0 + ar0) * 1024 + aj0 * 8;
  const u16* Bg1 = Bt + (size_t)(col0 + ar1) * 1024 + aj1 * 8;
  char* AsB = (char*)As;  char* BsB = (char*)Bs;
  char* aL0 = AsB + w * 1024;         char* aL1 = AsB + 4096 + w * 1024;
  char* bL0 = BsB + w * 1024;         char* bL1 = BsB + 4096 + w * 1024;

  int aoff[4], boff[4];
#pragma unroll
  for (int f = 0; f < 4; ++f) {
    aoff[f] = (wr + f * 16 + lrow) * 64 + lk * 16;
    boff[f] = (wc + f * 16 + lrow) * 64 + lk * 16;
  }

  for (int k0 = 0; k0 < 1024; k0 += 32) {
    if (k0) __syncthreads();
    ASYNC16(Ag0 + k0, aL0);
    ASYNC16(Ag1 + k0, aL1);
    ASYNC16(Bg0 + k0, bL0);
    ASYNC16(Bg1 + k0, bL1);
    asm volatile("s_waitcnt vmcnt(0)" ::: "memory");
    __syncthreads();

    s16x8 af[4], bfr[4];
#pragma unroll
    for (int f = 0; f < 4; ++f) af[f] = *(const s16x8*)(AsB + aoff[f]);
#pragma unroll
    for (int f = 0; f < 4; ++f) bfr[f] = *(const s16x8*)(BsB + boff[f]);
#pragma unroll
    for (int fm = 0; fm < 4; ++fm)
#pragma unroll
      for (int fn = 0; fn < 4; ++fn)
        acc[fm][fn] = __builtin_amdgcn_mfma_f32_16x16x32_bf16(
            af[fm], bfr[fn], acc[fm][fn], 0, 0, 0);
  }

  const int crow = lane >> 4;
  const int ccol = lane & 15;
#pragma unroll
  for (int fm = 0; fm < 4; ++fm)
#pragma unroll
    for (int fn = 0; fn < 4; ++fn) {
      size_t rb = (size_t)(row0 + wr + fm * 16 + crow * 4);
      int col = col0 + wc + fn * 16 + ccol;
      if (OUTMODE == 1) {
        u16* C = (u16*)Cv;
#pragma unroll
        for (int r = 0; r < 4; ++r)
          C[(rb + r) * ldc + col] = f2bf(acc[fm][fn][r]);
      } else {
        float* C = (float*)Cv;
#pragma unroll
        for (int r = 0; r < 4; ++r) {
          C[(rb + r) * ldc + col] = acc[fm][fn][r];
          if (OUTMODE == 2) Cbf[(rb + r) * ldc + col] = f2bf(acc[fm][fn][r]);
        }
      }
    }
}

// ---------- deltas = q2view[8192][1280] @ dwbf^T + db, MFMA 64x64 tiles -----
__global__ __launch_bounds__(256) void delta_mfma(
    const u16* __restrict__ Aq2, const u16* __restrict__ dwbf,
    const float* __restrict__ db, float* __restrict__ deltas)
{
  __shared__ __align__(16) u16 As[64 * 32];
  __shared__ __align__(16) u16 Bs[64 * 32];
  const int tid  = threadIdx.x;
  const int lane = tid & 63;
  const int w    = tid >> 6;
  const int row0 = blockIdx.x * 64;
  const int wr   = w * 16;
  const int lrow = lane & 15;
  const int lk   = lane >> 4;

  f32x4 acc[4];
#pragma unroll
  for (int j = 0; j < 4; ++j) acc[j] = (f32x4){0.f, 0.f, 0.f, 0.f};

  // staging: A 64 rows x 32k (256 chunks, 1/thread), B 64 rows x 32k (1/thread)
  const u16* Ag = Aq2  + (size_t)(row0 + (tid >> 2)) * 1280 + (tid & 3) * 8;
  const u16* Bg = dwbf + (size_t)(tid >> 2) * 1280 + (tid & 3) * 8;
  char* AsB = (char*)As;  char* BsB = (char*)Bs;
  char* aL = AsB + w * 1024;
  char* bL = BsB + w * 1024;

  const int aoff = (wr + lrow) * 64 + lk * 16;
  int boff[4];
#pragma unroll
  for (int f = 0; f < 4; ++f) boff[f] = (f * 16 + lrow) * 64 + lk * 16;

  for (int k0 = 0; k0 < 1280; k0 += 32) {
    if (k0) __syncthreads();
    ASYNC16(Ag + k0, aL);
    ASYNC16(Bg + k0, bL);
    asm volatile("s_waitcnt vmcnt(0)" ::: "memory");
    __syncthreads();

    s16x8 af = *(const s16x8*)(AsB + aoff);
#pragma unroll
    for (int fn = 0; fn < 4; ++fn) {
      s16x8 bfr = *(const s16x8*)(BsB + boff[fn]);
      acc[fn] = __builtin_amdgcn_mfma_f32_16x16x32_bf16(af, bfr, acc[fn], 0, 0, 0);
    }
  }

  const int crow = lane >> 4;
  const int ccol = lane & 15;
#pragma unroll
  for (int fn = 0; fn < 4; ++fn) {
    int col = fn * 16 + ccol;
    if (col < 60) {
      float d = db[col];
      size_t rb = (size_t)(row0 + wr + crow * 4);
#pragma unroll
      for (int r = 0; r < 4; ++r)
        deltas[(rb + r) * 60 + col] = acc[fn][r] + d;
    }
  }
}

// ---------- coords: pd = ref + deltas ; L2-normalize over the hi axis -------
__global__ void coords_kernel(const float* __restrict__ deltas,
                              float* __restrict__ vgx, float* __restrict__ vgy)
{
  int g = blockIdx.x * 256 + threadIdx.x;
  if (g >= 32 * 16 * 10 * 3) return;
  int kk = g % 3, tmp = g / 3;
  int s = tmp % 10; tmp /= 10;
  int wi = tmp % 16; int bnm = tmp / 16;
  float gxr = wi * (1.0f / 15.0f);
  float px[16], py[16];
  float sx = 0.f, sy = 0.f;
#pragma unroll
  for (int hi = 0; hi < 16; ++hi) {
    size_t base = ((size_t)((bnm * 16 + hi) * 16 + wi)) * 60 + (s * 3 + kk) * 2;
    float x = gxr + deltas[base];
    float y = hi * (1.0f / 15.0f) + deltas[base + 1];
    px[hi] = x; py[hi] = y;
    sx += x * x; sy += y * y;
  }
  float rx = 1.0f / fmaxf(sqrtf(sx), 1e-12f);
  float ry = 1.0f / fmaxf(sqrtf(sy), 1e-12f);
#pragma unroll
  for (int hi = 0; hi < 16; ++hi) {
    size_t o = ((size_t)((bnm * 16 + hi) * 16 + wi) * 10 + s) * 3 + kk;
    vgx[o] = px[hi] * rx;
    vgy[o] = py[hi] * ry;
  }
}

// ---------- fused: bilinear k-sample + qk + softmax + P@V -------------------
__global__ __launch_bounds__(256) void attn_kernel(
    const float* __restrict__ q2, const float* __restrict__ kp2,
    const u16* __restrict__ vp2, const float* __restrict__ vgx,
    const float* __restrict__ vgy, u16* __restrict__ headf,
    float* __restrict__ attn0)
{
  int bid = blockIdx.x;
  int m = bid >> 10, b = bid & 1023;
  int tid = threadIdx.x;

  __shared__ __align__(16) float qs[1280];
  __shared__ __align__(16) float ks[3840];
  __shared__ __align__(16) float vs[3840];
  __shared__ float qks[10][32];
  __shared__ float wst[30][4];
  __shared__ int cst[30][4];

  const float4* qsrc = (const float4*)(q2 + (size_t)bid * 1280);
  for (int i = tid; i < 320; i += 256) ((float4*)qs)[i] = qsrc[i];

  if (tid < 30) {
    int t = tid, kk = t / 10, sk = t % 10;
    size_t ci = ((size_t)bid * 10 + sk) * 3 + kk;
    float gx = vgx[ci], gy = vgy[ci];
    float ix = (gx + 1.0f) * 8.0f - 0.5f;
    float iy = (gy + 1.0f) * 8.0f - 0.5f;
    float x0f = floorf(ix), y0f = floorf(iy);
    float wx1 = ix - x0f, wx0 = 1.0f - wx1;
    float wy1 = iy - y0f, wy0 = 1.0f - wy1;
    float x1f = x0f + 1.0f, y1f = y0f + 1.0f;
    bool vx0 = (x0f >= 0.f) && (x0f <= 15.f);
    bool vx1 = (x1f >= 0.f) && (x1f <= 15.f);
    bool vy0 = (y0f >= 0.f) && (y0f <= 15.f);
    bool vy1 = (y1f >= 0.f) && (y1f <= 15.f);
    int x0 = min(max((int)x0f, 0), 15);
    int x1 = min(max((int)x1f, 0), 15);
    int y0 = min(max((int)y0f, 0), 15);
    int y1 = min(max((int)y1f, 0), 15);
    wst[t][0] = wx0 * wy0 * ((vx0 && vy0) ? 1.f : 0.f);
    wst[t][1] = wx1 * wy0 * ((vx1 && vy0) ? 1.f : 0.f);
    wst[t][2] = wx0 * wy1 * ((vx0 && vy1) ? 1.f : 0.f);
    wst[t][3] = wx1 * wy1 * ((vx1 && vy1) ? 1.f : 0.f);
    cst[t][0] = x0; cst[t][1] = x1; cst[t][2] = y0; cst[t][3] = y1;
  }

  for (int i = tid; i < 480; i += 256) {
    int t = i >> 4, off = (i & 15) * 8;
    int sv = t / 3, cv = t - sv * 3;
    u16x8 v = *(const u16x8*)(vp2 + ((size_t)(b * 10 + sv)) * 3072 +
                              m * 384 + cv * 128 + off);
    float* d = &vs[t * 128 + off];
#pragma unroll
    for (int r = 0; r < 8; ++r) d[r] = bf2f(v[r]);
  }
  __syncthreads();

  {
    int pb = (b >> 8) << 8;
    for (int i = tid; i < 960; i += 256) {
      int t = i >> 5, off = (i & 31) * 4;
      int sk = t % 10;
      int x0 = cst[t][0], x1 = cst[t][1], y0 = cst[t][2], y1 = cst[t][3];
      float w00 = wst[t][0], w10 = wst[t][1], w01 = wst[t][2], w11 = wst[t][3];
      size_t colo = (size_t)m * 128 + off;
      const float4 f00 = *(const float4*)&kp2[((size_t)((pb + y0 * 16 + x0) * 10 + sk)) * 1024 + colo];
      const float4 f10 = *(const float4*)&kp2[((size_t)((pb + y0 * 16 + x1) * 10 + sk)) * 1024 + colo];
      const float4 f01 = *(const float4*)&kp2[((size_t)((pb + y1 * 16 + x0) * 10 + sk)) * 1024 + colo];
      const float4 f11 = *(const float4*)&kp2[((size_t)((pb + y1 * 16 + x1) * 10 + sk)) * 1024 + colo];
      float4 acc;
      acc.x = w00 * f00.x + w10 * f10.x + w01 * f01.x + w11 * f11.x;
      acc.y = w00 * f00.y + w10 * f10.y + w01 * f01.y + w11 * f11.y;
      acc.z = w00 * f00.z + w10 * f10.z + w01 * f01.z + w11 * f11.z;
      acc.w = w00 * f00.w + w10 * f10.w + w01 * f01.w + w11 * f11.w;
      ((float4*)ks)[i] = acc;
    }
  }
  __syncthreads();

  for (int e = tid; e < 300; e += 256) {
    int s = e / 30, t = e % 30;
    const float4* qv = (const float4*)&qs[s * 128];
    const float4* kv = (const float4*)&ks[t * 128];
    float acc = 0.f;
#pragma unroll
    for (int j = 0; j < 32; ++j) {
      float4 a = qv[j], c = kv[j];
      acc += a.x * c.x + a.y * c.y + a.z * c.z + a.w * c.w;
    }
    qks[s][t] = acc * 0.08838834764831845f;
  }
  __syncthreads();

  if (tid < 10) {
    int s = tid;
    float mx = -1e30f;
    for (int t = 0; t < 30; ++t) mx = fmaxf(mx, qks[s][t]);
    float sum = 0.f;
    for (int t = 0; t < 30; ++t) {
      float e = __expf(qks[s][t] - mx);
      qks[s][t] = e; sum += e;
    }
    float inv = 1.0f / sum;
    for (int t = 0; t < 30; ++t) qks[s][t] *= inv;
  }
  __syncthreads();
  if (tid < 30) attn0[(size_t)bid * 30 + tid] = qks[0][tid];

  for (int i = tid; i < 320; i += 256) {
    int s = i >> 5, off = (i & 31) * 4;
    float4 acc = {0.f, 0.f, 0.f, 0.f};
    for (int t = 0; t < 30; ++t) {
      float a = qks[s][t];
      const float4 v = *(const float4*)&vs[t * 128 + off];
      acc.x += a * v.x; acc.y += a * v.y; acc.z += a * v.z; acc.w += a * v.w;
    }
    u16x4 o;
    o[0] = f2bf(acc.x); o[1] = f2bf(acc.y); o[2] = f2bf(acc.z); o[3] = f2bf(acc.w);
    *(u16x4*)&headf[((size_t)(b * 10 + s)) * 1024 + m * 128 + off] = o;
  }
}

// ---------- attn_map[b][t] = mean_m attn0[m][b][t] --------------------------
__global__ void attnmap_kernel(const float* __restrict__ attn0, float* __restrict__ outa)
{
  int i = blockIdx.x * 256 + threadIdx.x;
  if (i >= 30720) return;
  int b = i / 30, t = i % 30;
  float s = 0.f;
  for (int mm = 0; mm < 8; ++mm) s += attn0[((size_t)mm * 1024 + b) * 30 + t];
  outa[i] = 0.125f * s;
}

// ---------------------------------------------------------------------------
extern "C" void kernel_launch(void* const* d_in, const int* in_sizes, int n_in,
                              void* d_out, int out_size, void* d_ws, size_t ws_size,
                              hipStream_t stream)
{
  const float* q  = (const float*)d_in[0];
  const float* Wq = (const float*)d_in[1];
  const float* Wk = (const float*)d_in[2];
  const float* Wv = (const float*)d_in[3];
  const float* Wo = (const float*)d_in[4];
  const float* dw = (const float*)d_in[5];
  const float* db = (const float*)d_in[6];
  float* out = (float*)d_out;
  float* attn_out = out + 10485760;

  // workspace layout (bytes): total ~218 MB
  char* p = (char*)d_ws;
  u16*   Abf   = (u16*)p;   p += 20971520;   // [10240][1024] bf16
  u16*   Wcat  = (u16*)p;   p += 12582912;   // [6144][1024] bf16 (B^T fused)
  float* q2    = (float*)p; p += 41943040;   // [10240][1024] fp32
  u16*   q2bf  = (u16*)p;  p += 20971520;    // [10240][1024] bf16 (= [8192][1280])
  float* kp2   = (float*)p; p += 41943040;   // [10240][1024] fp32
  u16*   vp2   = (u16*)p;   p += 62914560;   // [10240][3072] bf16
  u16*   headf = (u16*)p;   p += 20971520;   // [10240][1024] bf16
  u16*   dwbf  = (u16*)p;   p += 163840;     // [64][1280] bf16
  float* dels  = (float*)p; p += 1966080;    // [8192][60]
  float* vgxp  = (float*)p; p += 983040;
  float* vgyp  = (float*)p; p += 983040;
  float* attn0 = (float*)p; p += 983040;

  conv_a<<<dim3(5120), dim3(256), 0, stream>>>(q, Abf, 1310720);
  conv_w<<<dim3(3072), dim3(256), 0, stream>>>(Wq, Wk, Wv, Wo, Wcat);
  conv_dw<<<dim3(40), dim3(256), 0, stream>>>(dw, dwbf);

  // q2 (fp32+bf16), kp2 (fp32), vp2 (bf16)
  gemm_mfma<2><<<dim3(80, 8), dim3(256), 0, stream>>>(Abf, Wcat, q2, q2bf, 1024);
  gemm_mfma<0><<<dim3(80, 8), dim3(256), 0, stream>>>(Abf, Wcat + (size_t)1024 * 1024, kp2, nullptr, 1024);
  gemm_mfma<1><<<dim3(80, 24), dim3(256), 0, stream>>>(Abf, Wcat + (size_t)2048 * 1024, vp2, nullptr, 3072);

  delta_mfma<<<dim3(128), dim3(256), 0, stream>>>(q2bf, dwbf, db, dels);
  coords_kernel<<<dim3(60), dim3(256), 0, stream>>>(dels, vgxp, vgyp);
  attn_kernel<<<dim3(8192), dim3(256), 0, stream>>>(q2, kp2, vp2, vgxp, vgyp, headf, attn0);
  attnmap_kernel<<<dim3(120), dim3(256), 0, stream>>>(attn0, attn_out);

  gemm_mfma<0><<<dim3(80, 8), dim3(256), 0, stream>>>(headf, Wcat + (size_t)5120 * 1024, out, nullptr, 1024);
}

// Round 4
// 274.955 us; speedup vs baseline: 7.6020x; 1.6006x over previous
//
#include <hip/hip_runtime.h>

// ---------------------------------------------------------------------------
// MultiHeadAttention_50646254354439 — R4: MFMA attention (qk+PV on matrix core)
// Dims: B=1024, S=10, D=1024, E=1024, V=KD=128, H=M=8, K=3, HI=WI=16
// N = B*S = 10240
// ---------------------------------------------------------------------------

typedef float    f32x4 __attribute__((ext_vector_type(4)));
typedef short    s16x8 __attribute__((ext_vector_type(8)));
typedef unsigned short u16x8 __attribute__((ext_vector_type(8)));
typedef unsigned short u16x4 __attribute__((ext_vector_type(4)));
typedef unsigned short u16;

__device__ __forceinline__ u16 f2bf(float f) {   // RNE float->bf16
  union { float f; unsigned u; } x; x.f = f;
  unsigned r = x.u + 0x7FFFu + ((x.u >> 16) & 1u);
  return (u16)(r >> 16);
}
__device__ __forceinline__ float bf2f(u16 u) {
  union { unsigned u; float f; } x; x.u = ((unsigned)u) << 16;
  return x.f;
}

#define ASYNC16(g, l) __builtin_amdgcn_global_load_lds(                       \
    (const __attribute__((address_space(1))) void*)(g),                       \
    (__attribute__((address_space(3))) void*)(l), 16, 0, 0)

// ---------- fp32 -> bf16 elementwise (A matrix: q, row-major [10240][1024]) -
__global__ __launch_bounds__(256) void conv_a(
    const float* __restrict__ src, u16* __restrict__ dst, int n8)
{
  int i = blockIdx.x * 256 + threadIdx.x;
  if (i >= n8) return;
  const float4* s = (const float4*)src + (size_t)i * 2;
  float4 a = s[0], b = s[1];
  u16x8 o;
  o[0] = f2bf(a.x); o[1] = f2bf(a.y); o[2] = f2bf(a.z); o[3] = f2bf(a.w);
  o[4] = f2bf(b.x); o[5] = f2bf(b.y); o[6] = f2bf(b.z); o[7] = f2bf(b.w);
  *(u16x8*)(dst + (size_t)i * 8) = o;
}

// ---------- build fused B^T (K-contiguous) weight matrix, bf16 --------------
__global__ __launch_bounds__(256) void conv_w(
    const float* __restrict__ Wq, const float* __restrict__ Wk,
    const float* __restrict__ Wv, const float* __restrict__ Wo,
    u16* __restrict__ Wcat)
{
  int i = blockIdx.x * 256 + threadIdx.x;   // 6144*128 = 786432 threads
  if (i >= 6144 * 128) return;
  int c = i >> 7;
  int d0 = (i & 127) * 8;
  const float* src; int stride;
  if (c < 1024)      { int kq = c >> 3, h = c & 7;
                       src = Wq + (size_t)h * 131072 + kq;      stride = 128; }
  else if (c < 2048) { int j = c - 1024; int h = j >> 7, k = j & 127;
                       src = Wk + (size_t)h * 131072 + k;       stride = 128; }
  else if (c < 5120) { int j = c - 2048; int h = j / 384, cc = j - h * 384;
                       src = Wv + (size_t)h * 393216 + cc;      stride = 384; }
  else               { int e = c - 5120;
                       src = Wo + e;                            stride = 1024; }
  u16x8 o;
#pragma unroll
  for (int r = 0; r < 8; ++r) o[r] = f2bf(src[(size_t)(d0 + r) * stride]);
  *(u16x8*)(Wcat + (size_t)c * 1024 + d0) = o;
}

// ---------- dw -> bf16 [64][1280] (rows >=60 dummy=row0, never written) -----
__global__ __launch_bounds__(256) void conv_dw(
    const float* __restrict__ dw, u16* __restrict__ dwbf)
{
  int i = blockIdx.x * 256 + threadIdx.x;   // 64*160 = 10240 chunks
  if (i >= 10240) return;
  int row = i / 160, ch = i - row * 160;
  int srow = (row < 60) ? row : 0;
  const float4* s = (const float4*)(dw + (size_t)srow * 1280 + ch * 8);
  float4 a = s[0], b = s[1];
  u16x8 o;
  o[0] = f2bf(a.x); o[1] = f2bf(a.y); o[2] = f2bf(a.z); o[3] = f2bf(a.w);
  o[4] = f2bf(b.x); o[5] = f2bf(b.y); o[6] = f2bf(b.z); o[7] = f2bf(b.w);
  *(u16x8*)(dwbf + (size_t)row * 1280 + ch * 8) = o;
}

// ---------- bf16 MFMA GEMM (m97 structure): C = A @ Bt^T --------------------
// OUTMODE: 0 = fp32 C; 1 = bf16 C
template<int OUTMODE>
__global__ __launch_bounds__(256) void gemm_mfma(
    const u16* __restrict__ A, const u16* __restrict__ Bt,
    void* __restrict__ Cv, int ldc)
{
  __shared__ __align__(16) u16 As[128 * 32];
  __shared__ __align__(16) u16 Bs[128 * 32];
  const int tid  = threadIdx.x;
  const int lane = tid & 63;
  const int w    = tid >> 6;
  const int row0 = blockIdx.x * 128;
  const int col0 = blockIdx.y * 128;
  const int wr   = (w >> 1) * 64;
  const int wc   = (w & 1) * 64;
  const int lrow = lane & 15;
  const int lk   = lane >> 4;

  f32x4 acc[4][4];
#pragma unroll
  for (int i = 0; i < 4; ++i)
#pragma unroll
    for (int j = 0; j < 4; ++j) acc[i][j] = (f32x4){0.f, 0.f, 0.f, 0.f};

  const int c0 = tid, c1 = 256 + tid;
  const int ar0 = c0 >> 2, aj0 = c0 & 3;
  const int ar1 = c1 >> 2, aj1 = c1 & 3;
  const u16* Ag0 = A  + (size_t)(row0 + ar0) * 1024 + aj0 * 8;
  const u16* Ag1 = A  + (size_t)(row0 + ar1) * 1024 + aj1 * 8;
  const u16* Bg0 = Bt + (size_t)(col0 + ar0) * 1024 + aj0 * 8;
  const u16* Bg1 = Bt + (size_t)(col0 + ar1) * 1024 + aj1 * 8;
  char* AsB = (char*)As;  char* BsB = (char*)Bs;
  char* aL0 = AsB + w * 1024;         char* aL1 = AsB + 4096 + w * 1024;
  char* bL0 = BsB + w * 1024;         char* bL1 = BsB + 4096 + w * 1024;

  int aoff[4], boff[4];
#pragma unroll
  for (int f = 0; f < 4; ++f) {
    aoff[f] = (wr + f * 16 + lrow) * 64 + lk * 16;
    boff[f] = (wc + f * 16 + lrow) * 64 + lk * 16;
  }

  for (int k0 = 0; k0 < 1024; k0 += 32) {
    if (k0) __syncthreads();
    ASYNC16(Ag0 + k0, aL0);
    ASYNC16(Ag1 + k0, aL1);
    ASYNC16(Bg0 + k0, bL0);
    ASYNC16(Bg1 + k0, bL1);
    asm volatile("s_waitcnt vmcnt(0)" ::: "memory");
    __syncthreads();

    s16x8 af[4], bfr[4];
#pragma unroll
    for (int f = 0; f < 4; ++f) af[f] = *(const s16x8*)(AsB + aoff[f]);
#pragma unroll
    for (int f = 0; f < 4; ++f) bfr[f] = *(const s16x8*)(BsB + boff[f]);
#pragma unroll
    for (int fm = 0; fm < 4; ++fm)
#pragma unroll
      for (int fn = 0; fn < 4; ++fn)
        acc[fm][fn] = __builtin_amdgcn_mfma_f32_16x16x32_bf16(
            af[fm], bfr[fn], acc[fm][fn], 0, 0, 0);
  }

  const int crow = lane >> 4;
  const int ccol = lane & 15;
#pragma unroll
  for (int fm = 0; fm < 4; ++fm)
#pragma unroll
    for (int fn = 0; fn < 4; ++fn) {
      size_t rb = (size_t)(row0 + wr + fm * 16 + crow * 4);
      int col = col0 + wc + fn * 16 + ccol;
      if (OUTMODE == 1) {
        u16* C = (u16*)Cv;
#pragma unroll
        for (int r = 0; r < 4; ++r)
          C[(rb + r) * ldc + col] = f2bf(acc[fm][fn][r]);
      } else {
        float* C = (float*)Cv;
#pragma unroll
        for (int r = 0; r < 4; ++r)
          C[(rb + r) * ldc + col] = acc[fm][fn][r];
      }
    }
}

// ---------- deltas = q2view[8192][1280] @ dwbf^T + db, MFMA 64x64 tiles -----
__global__ __launch_bounds__(256) void delta_mfma(
    const u16* __restrict__ Aq2, const u16* __restrict__ dwbf,
    const float* __restrict__ db, float* __restrict__ deltas)
{
  __shared__ __align__(16) u16 As[64 * 32];
  __shared__ __align__(16) u16 Bs[64 * 32];
  const int tid  = threadIdx.x;
  const int lane = tid & 63;
  const int w    = tid >> 6;
  const int row0 = blockIdx.x * 64;
  const int wr   = w * 16;
  const int lrow = lane & 15;
  const int lk   = lane >> 4;

  f32x4 acc[4];
#pragma unroll
  for (int j = 0; j < 4; ++j) acc[j] = (f32x4){0.f, 0.f, 0.f, 0.f};

  const u16* Ag = Aq2  + (size_t)(row0 + (tid >> 2)) * 1280 + (tid & 3) * 8;
  const u16* Bg = dwbf + (size_t)(tid >> 2) * 1280 + (tid & 3) * 8;
  char* AsB = (char*)As;  char* BsB = (char*)Bs;
  char* aL = AsB + w * 1024;
  char* bL = BsB + w * 1024;

  const int aoff = (wr + lrow) * 64 + lk * 16;
  int boff[4];
#pragma unroll
  for (int f = 0; f < 4; ++f) boff[f] = (f * 16 + lrow) * 64 + lk * 16;

  for (int k0 = 0; k0 < 1280; k0 += 32) {
    if (k0) __syncthreads();
    ASYNC16(Ag + k0, aL);
    ASYNC16(Bg + k0, bL);
    asm volatile("s_waitcnt vmcnt(0)" ::: "memory");
    __syncthreads();

    s16x8 af = *(const s16x8*)(AsB + aoff);
#pragma unroll
    for (int fn = 0; fn < 4; ++fn) {
      s16x8 bfr = *(const s16x8*)(BsB + boff[fn]);
      acc[fn] = __builtin_amdgcn_mfma_f32_16x16x32_bf16(af, bfr, acc[fn], 0, 0, 0);
    }
  }

  const int crow = lane >> 4;
  const int ccol = lane & 15;
#pragma unroll
  for (int fn = 0; fn < 4; ++fn) {
    int col = fn * 16 + ccol;
    if (col < 60) {
      float d = db[col];
      size_t rb = (size_t)(row0 + wr + crow * 4);
#pragma unroll
      for (int r = 0; r < 4; ++r)
        deltas[(rb + r) * 60 + col] = acc[fn][r] + d;
    }
  }
}

// ---------- coords: pd = ref + deltas ; L2-normalize over the hi axis -------
__global__ void coords_kernel(const float* __restrict__ deltas,
                              float* __restrict__ vgx, float* __restrict__ vgy)
{
  int g = blockIdx.x * 256 + threadIdx.x;
  if (g >= 32 * 16 * 10 * 3) return;
  int kk = g % 3, tmp = g / 3;
  int s = tmp % 10; tmp /= 10;
  int wi = tmp % 16; int bnm = tmp / 16;
  float gxr = wi * (1.0f / 15.0f);
  float px[16], py[16];
  float sx = 0.f, sy = 0.f;
#pragma unroll
  for (int hi = 0; hi < 16; ++hi) {
    size_t base = ((size_t)((bnm * 16 + hi) * 16 + wi)) * 60 + (s * 3 + kk) * 2;
    float x = gxr + deltas[base];
    float y = hi * (1.0f / 15.0f) + deltas[base + 1];
    px[hi] = x; py[hi] = y;
    sx += x * x; sy += y * y;
  }
  float rx = 1.0f / fmaxf(sqrtf(sx), 1e-12f);
  float ry = 1.0f / fmaxf(sqrtf(sy), 1e-12f);
#pragma unroll
  for (int hi = 0; hi < 16; ++hi) {
    size_t o = ((size_t)((bnm * 16 + hi) * 16 + wi) * 10 + s) * 3 + kk;
    vgx[o] = px[hi] * rx;
    vgy[o] = py[hi] * ry;
  }
}

// ---------- MFMA attention: sample K (bilinear) + qk + softmax + PV ---------
// one block per (m,b); 4 waves. kpbf bf16 [10240][1024]; q2bf bf16; vp2 bf16.
__global__ __launch_bounds__(256) void attn_mfma(
    const u16* __restrict__ q2bf, const u16* __restrict__ kpbf,
    const u16* __restrict__ vp2, const float* __restrict__ vgx,
    const float* __restrict__ vgy, u16* __restrict__ headf,
    float* __restrict__ attn0)
{
  const int bid = blockIdx.x;
  const int m = bid >> 10, b = bid & 1023;
  const int tid = threadIdx.x;
  const int lane = tid & 63;
  const int w = tid >> 6;

  __shared__ __align__(16) u16 ksb[32][136];   // sampled K rows, bf16
  __shared__ __align__(16) u16 vt[128][32];    // V^T, col-swizzled t^8(v&3)
  __shared__ __align__(16) u16 pl[16][40];     // P bf16 (A-frag layout)
  __shared__ float wst[30][4];
  __shared__ int   cst[30][4];

  // preload Q A-frags from global (wave 0 only); rows>=10 read ws garbage (ok)
  s16x8 aq[4];
  if (w == 0) {
    const u16* qb = q2bf + (size_t)bid * 1280 + (lane & 15) * 128 + (lane >> 4) * 8;
#pragma unroll
    for (int kk = 0; kk < 4; ++kk) aq[kk] = *(const s16x8*)(qb + kk * 32);
  }

  // bilinear coefficients (t = kk*10 + sk)
  if (tid < 30) {
    int t = tid, kk = t / 10, sk = t % 10;
    size_t ci = ((size_t)bid * 10 + sk) * 3 + kk;
    float gx = vgx[ci], gy = vgy[ci];
    float ix = (gx + 1.0f) * 8.0f - 0.5f;
    float iy = (gy + 1.0f) * 8.0f - 0.5f;
    float x0f = floorf(ix), y0f = floorf(iy);
    float wx1 = ix - x0f, wx0 = 1.0f - wx1;
    float wy1 = iy - y0f, wy0 = 1.0f - wy1;
    float x1f = x0f + 1.0f, y1f = y0f + 1.0f;
    bool vx0 = (x0f >= 0.f) && (x0f <= 15.f);
    bool vx1 = (x1f >= 0.f) && (x1f <= 15.f);
    bool vy0 = (y0f >= 0.f) && (y0f <= 15.f);
    bool vy1 = (y1f >= 0.f) && (y1f <= 15.f);
    int x0 = min(max((int)x0f, 0), 15);
    int x1 = min(max((int)x1f, 0), 15);
    int y0 = min(max((int)y0f, 0), 15);
    int y1 = min(max((int)y1f, 0), 15);
    wst[t][0] = wx0 * wy0 * ((vx0 && vy0) ? 1.f : 0.f);
    wst[t][1] = wx1 * wy0 * ((vx1 && vy0) ? 1.f : 0.f);
    wst[t][2] = wx0 * wy1 * ((vx0 && vy1) ? 1.f : 0.f);
    wst[t][3] = wx1 * wy1 * ((vx1 && vy1) ? 1.f : 0.f);
    cst[t][0] = x0; cst[t][1] = x1; cst[t][2] = y0; cst[t][3] = y1;
  }
  __syncthreads();

  // stage V^T (swizzled): 512 items, t = i&31 (t>=30 -> zeros), c = i>>5
  for (int i = tid; i < 512; i += 256) {
    int t = i & 31, c = i >> 5;
    u16x8 v = (u16x8){0, 0, 0, 0, 0, 0, 0, 0};
    if (t < 30) {
      int sv = t / 3, cv = t - sv * 3;
      v = *(const u16x8*)(vp2 + ((size_t)(b * 10 + sv)) * 3072 +
                          m * 384 + cv * 128 + c * 8);
    }
#pragma unroll
    for (int r = 0; r < 8; ++r)
      vt[8 * c + r][t ^ (8 * (r & 3))] = v[r];
  }

  // bilinear-sample K rows -> ksb bf16: 480 items (t 0..29, c 0..15: 8 feats)
  {
    int pb = (b >> 8) << 8;
    for (int i = tid; i < 480; i += 256) {
      int t = i >> 4, c = i & 15;
      int sk = t % 10;
      int x0 = cst[t][0], x1 = cst[t][1], y0 = cst[t][2], y1 = cst[t][3];
      float w00 = wst[t][0], w10 = wst[t][1], w01 = wst[t][2], w11 = wst[t][3];
      size_t colo = (size_t)m * 128 + c * 8;
      const u16x8 f00 = *(const u16x8*)&kpbf[((size_t)((pb + y0 * 16 + x0) * 10 + sk)) * 1024 + colo];
      const u16x8 f10 = *(const u16x8*)&kpbf[((size_t)((pb + y0 * 16 + x1) * 10 + sk)) * 1024 + colo];
      const u16x8 f01 = *(const u16x8*)&kpbf[((size_t)((pb + y1 * 16 + x0) * 10 + sk)) * 1024 + colo];
      const u16x8 f11 = *(const u16x8*)&kpbf[((size_t)((pb + y1 * 16 + x1) * 10 + sk)) * 1024 + colo];
      u16x8 o;
#pragma unroll
      for (int r = 0; r < 8; ++r) {
        float acc = w00 * bf2f(f00[r]) + w10 * bf2f(f10[r]) +
                    w01 * bf2f(f01[r]) + w11 * bf2f(f11[r]);
        o[r] = f2bf(acc);
      }
      *(u16x8*)&ksb[t][c * 8] = o;
    }
  }
  __syncthreads();

  // wave 0: qk MFMA (M=16,N=32,K=128) + in-register softmax + P->LDS
  if (w == 0) {
    f32x4 dq[2];
    dq[0] = (f32x4){0.f, 0.f, 0.f, 0.f};
    dq[1] = (f32x4){0.f, 0.f, 0.f, 0.f};
    const int lr = lane & 15, g = lane >> 4;
#pragma unroll
    for (int kk = 0; kk < 4; ++kk) {
      s16x8 b0 = *(const s16x8*)&ksb[lr][g * 8 + kk * 32];
      s16x8 b1 = *(const s16x8*)&ksb[16 + lr][g * 8 + kk * 32];
      dq[0] = __builtin_amdgcn_mfma_f32_16x16x32_bf16(aq[kk], b0, dq[0], 0, 0, 0);
      dq[1] = __builtin_amdgcn_mfma_f32_16x16x32_bf16(aq[kk], b1, dq[1], 0, 0, 0);
    }
    // lane holds D[s = g*4+r][t = lr + 16*f]; softmax over t (30 valid)
    float p[2][4];
#pragma unroll
    for (int f = 0; f < 2; ++f) {
      int t = lr + 16 * f;
#pragma unroll
      for (int r = 0; r < 4; ++r) {
        float v = dq[f][r] * 0.08838834764831845f;
        p[f][r] = (t < 30) ? v : -1e30f;
      }
    }
#pragma unroll
    for (int r = 0; r < 4; ++r) {
      float mx = fmaxf(p[0][r], p[1][r]);
#pragma unroll
      for (int msk = 1; msk <= 8; msk <<= 1) mx = fmaxf(mx, __shfl_xor(mx, msk));
      float e0 = __expf(p[0][r] - mx);
      float e1 = __expf(p[1][r] - mx);
      float sm = e0 + e1;
#pragma unroll
      for (int msk = 1; msk <= 8; msk <<= 1) sm += __shfl_xor(sm, msk);
      float inv = 1.0f / sm;
      p[0][r] = e0 * inv;
      p[1][r] = e1 * inv;
    }
    // attn0 (row s=0 lives in g=0, r=0)
    if (g == 0) {
      attn0[(size_t)bid * 30 + lr] = p[0][0];
      if (lr < 14) attn0[(size_t)bid * 30 + 16 + lr] = p[1][0];
    }
    // P -> LDS bf16 in A-frag layout
#pragma unroll
    for (int f = 0; f < 2; ++f)
#pragma unroll
      for (int r = 0; r < 4; ++r)
        pl[g * 4 + r][lr + 16 * f] = f2bf(p[f][r]);
  }
  __syncthreads();

  // PV: all waves; frags fv = 2w, 2w+1 (v0 = fv*16); K=32 one step
  const int lr = lane & 15, g = lane >> 4;
  s16x8 pa = *(const s16x8*)&pl[lr][g * 8];
#pragma unroll
  for (int qf = 0; qf < 2; ++qf) {
    int fv = w * 2 + qf;
    int v = fv * 16 + lr;
    s16x8 bv = *(const s16x8*)&vt[v][8 * (g ^ (v & 3))];
    f32x4 acc = (f32x4){0.f, 0.f, 0.f, 0.f};
    acc = __builtin_amdgcn_mfma_f32_16x16x32_bf16(pa, bv, acc, 0, 0, 0);
#pragma unroll
    for (int r = 0; r < 4; ++r) {
      int s = g * 4 + r;
      if (s < 10)
        headf[((size_t)(b * 10 + s)) * 1024 + m * 128 + v] = f2bf(acc[r]);
    }
  }
}

// ---------- attn_map[b][t] = mean_m attn0[m][b][t] --------------------------
__global__ void attnmap_kernel(const float* __restrict__ attn0, float* __restrict__ outa)
{
  int i = blockIdx.x * 256 + threadIdx.x;
  if (i >= 30720) return;
  int b = i / 30, t = i % 30;
  float s = 0.f;
  for (int mm = 0; mm < 8; ++mm) s += attn0[((size_t)mm * 1024 + b) * 30 + t];
  outa[i] = 0.125f * s;
}

// ---------------------------------------------------------------------------
extern "C" void kernel_launch(void* const* d_in, const int* in_sizes, int n_in,
                              void* d_out, int out_size, void* d_ws, size_t ws_size,
                              hipStream_t stream)
{
  const float* q  = (const float*)d_in[0];
  const float* Wq = (const float*)d_in[1];
  const float* Wk = (const float*)d_in[2];
  const float* Wv = (const float*)d_in[3];
  const float* Wo = (const float*)d_in[4];
  const float* dw = (const float*)d_in[5];
  const float* db = (const float*)d_in[6];
  float* out = (float*)d_out;
  float* attn_out = out + 10485760;

  // workspace layout (bytes): total ~145 MB
  char* p = (char*)d_ws;
  u16*   Abf   = (u16*)p;   p += 20971520;   // [10240][1024] bf16
  u16*   Wcat  = (u16*)p;   p += 12582912;   // [6144][1024] bf16 (B^T fused)
  u16*   q2bf  = (u16*)p;   p += 20971520;   // [10240][1024] bf16 (= [8192][1280])
  u16*   kpbf  = (u16*)p;   p += 20971520;   // [10240][1024] bf16
  u16*   vp2   = (u16*)p;   p += 62914560;   // [10240][3072] bf16
  u16*   headf = (u16*)p;   p += 20971520;   // [10240][1024] bf16
  u16*   dwbf  = (u16*)p;   p += 163840;     // [64][1280] bf16
  float* dels  = (float*)p; p += 1966080;    // [8192][60]
  float* vgxp  = (float*)p; p += 983040;
  float* vgyp  = (float*)p; p += 983040;
  float* attn0 = (float*)p; p += 983040;

  conv_a<<<dim3(5120), dim3(256), 0, stream>>>(q, Abf, 1310720);
  conv_w<<<dim3(3072), dim3(256), 0, stream>>>(Wq, Wk, Wv, Wo, Wcat);
  conv_dw<<<dim3(40), dim3(256), 0, stream>>>(dw, dwbf);

  gemm_mfma<1><<<dim3(80, 8), dim3(256), 0, stream>>>(Abf, Wcat, q2bf, 1024);
  gemm_mfma<1><<<dim3(80, 8), dim3(256), 0, stream>>>(Abf, Wcat + (size_t)1024 * 1024, kpbf, 1024);
  gemm_mfma<1><<<dim3(80, 24), dim3(256), 0, stream>>>(Abf, Wcat + (size_t)2048 * 1024, vp2, 3072);

  delta_mfma<<<dim3(128), dim3(256), 0, stream>>>(q2bf, dwbf, db, dels);
  coords_kernel<<<dim3(60), dim3(256), 0, stream>>>(dels, vgxp, vgyp);
  attn_mfma<<<dim3(8192), dim3(256), 0, stream>>>(q2bf, kpbf, vp2, vgxp, vgyp, headf, attn0);
  attnmap_kernel<<<dim3(120), dim3(256), 0, stream>>>(attn0, attn_out);

  gemm_mfma<0><<<dim3(80, 8), dim3(256), 0, stream>>>(headf, Wcat + (size_t)5120 * 1024, out, 1024);
}

// Round 5
// 264.632 us; speedup vs baseline: 7.8985x; 1.0390x over previous
//
#include <hip/hip_runtime.h>

// ---------------------------------------------------------------------------
// MultiHeadAttention_50646254354439 — R5: pipelined GEMM (T2+T3+T4+T5)
// Dims: B=1024, S=10, D=1024, E=1024, V=KD=128, H=M=8, K=3, HI=WI=16
// N = B*S = 10240. proj = [10240][5120] bf16 = q2|kp|vp fused.
// ---------------------------------------------------------------------------

typedef float    f32x4 __attribute__((ext_vector_type(4)));
typedef short    s16x8 __attribute__((ext_vector_type(8)));
typedef unsigned short u16x8 __attribute__((ext_vector_type(8)));
typedef unsigned short u16;

__device__ __forceinline__ u16 f2bf(float f) {   // RNE float->bf16
  union { float f; unsigned u; } x; x.f = f;
  unsigned r = x.u + 0x7FFFu + ((x.u >> 16) & 1u);
  return (u16)(r >> 16);
}
__device__ __forceinline__ float bf2f(u16 u) {
  union { unsigned u; float f; } x; x.u = ((unsigned)u) << 16;
  return x.f;
}

#define ASYNC16(g, l) __builtin_amdgcn_global_load_lds(                       \
    (const __attribute__((address_space(1))) void*)(g),                       \
    (__attribute__((address_space(3))) void*)(l), 16, 0, 0)

// ---------- fp32 -> bf16 elementwise ----------------------------------------
__global__ __launch_bounds__(256) void conv_a(
    const float* __restrict__ src, u16* __restrict__ dst, int n8)
{
  int i = blockIdx.x * 256 + threadIdx.x;
  if (i >= n8) return;
  const float4* s = (const float4*)src + (size_t)i * 2;
  float4 a = s[0], b = s[1];
  u16x8 o;
  o[0] = f2bf(a.x); o[1] = f2bf(a.y); o[2] = f2bf(a.z); o[3] = f2bf(a.w);
  o[4] = f2bf(b.x); o[5] = f2bf(b.y); o[6] = f2bf(b.z); o[7] = f2bf(b.w);
  *(u16x8*)(dst + (size_t)i * 8) = o;
}

// ---------- build fused B^T (K-contiguous) weight matrix, bf16 --------------
__global__ __launch_bounds__(256) void conv_w(
    const float* __restrict__ Wq, const float* __restrict__ Wk,
    const float* __restrict__ Wv, const float* __restrict__ Wo,
    u16* __restrict__ Wcat)
{
  int i = blockIdx.x * 256 + threadIdx.x;   // 6144*128 = 786432 threads
  if (i >= 6144 * 128) return;
  int c = i >> 7;
  int d0 = (i & 127) * 8;
  const float* src; int stride;
  if (c < 1024)      { int kq = c >> 3, h = c & 7;
                       src = Wq + (size_t)h * 131072 + kq;      stride = 128; }
  else if (c < 2048) { int j = c - 1024; int h = j >> 7, k = j & 127;
                       src = Wk + (size_t)h * 131072 + k;       stride = 128; }
  else if (c < 5120) { int j = c - 2048; int h = j / 384, cc = j - h * 384;
                       src = Wv + (size_t)h * 393216 + cc;      stride = 384; }
  else               { int e = c - 5120;
                       src = Wo + e;                            stride = 1024; }
  u16x8 o;
#pragma unroll
  for (int r = 0; r < 8; ++r) o[r] = f2bf(src[(size_t)(d0 + r) * stride]);
  *(u16x8*)(Wcat + (size_t)c * 1024 + d0) = o;
}

// ---------- dw -> bf16 [64][1280] (rows >=60 dummy=row0, never written) -----
__global__ __launch_bounds__(256) void conv_dw(
    const float* __restrict__ dw, u16* __restrict__ dwbf)
{
  int i = blockIdx.x * 256 + threadIdx.x;   // 64*160 = 10240 chunks
  if (i >= 10240) return;
  int row = i / 160, ch = i - row * 160;
  int srow = (row < 60) ? row : 0;
  const float4* s = (const float4*)(dw + (size_t)srow * 1280 + ch * 8);
  float4 a = s[0], b = s[1];
  u16x8 o;
  o[0] = f2bf(a.x); o[1] = f2bf(a.y); o[2] = f2bf(a.z); o[3] = f2bf(a.w);
  o[4] = f2bf(b.x); o[5] = f2bf(b.y); o[6] = f2bf(b.z); o[7] = f2bf(b.w);
  *(u16x8*)(dwbf + (size_t)row * 1280 + ch * 8) = o;
}

// ---------- pipelined bf16 MFMA GEMM: C = A @ Bt^T --------------------------
// BM=256 BN=128 BK=64, 8 waves, per-wave 64x64. Triple-buffered LDS (144 KB),
// counted vmcnt(6) (2 K-tiles in flight), XOR slot-swizzle (slot ^= row&7)
// applied via pre-swizzled GLOBAL source + swizzled ds_read (rule 21).
// K fixed = 1024 (16 tiles). A [M][1024] bf16; Bt [N][1024] bf16.
template<int OUTBF>
__global__ __launch_bounds__(512) void gemm_pipe(
    const u16* __restrict__ A, const u16* __restrict__ Bt,
    void* __restrict__ Cv, int ldc)
{
  extern __shared__ __align__(16) char smem[];   // 147456 B
  const int tid = threadIdx.x;
  const int l   = tid & 63;
  const int wv  = tid >> 6;
  const int row0 = blockIdx.x * 256;
  const int col0 = blockIdx.y * 128;
  const int wr = (wv >> 1) * 64;
  const int wc = (wv & 1) * 64;
  const int lrow = l & 15, lk = l >> 4;

  // staging lane constants: dest slot l&7 holds global slot (l&7)^(l>>3)
  const int gro   = l >> 3;
  const int gslot = (l & 7) ^ gro;
  const u16* Asrc = A  + (size_t)(row0 + gro) * 1024 + gslot * 8;
  const u16* Bsrc = Bt + (size_t)(col0 + gro) * 1024 + gslot * 8;

  // ds-read byte offsets (swizzled): slot s read at (s ^ (row&7))*16
  const int sw0 = ((0 + lk) ^ (lrow & 7)) * 16;
  const int sw1 = ((4 + lk) ^ (lrow & 7)) * 16;
  const int arow = (wr + lrow) * 128;
  const int brow = (wc + lrow) * 128;

  f32x4 acc[4][4];
#pragma unroll
  for (int i = 0; i < 4; ++i)
#pragma unroll
    for (int j = 0; j < 4; ++j) acc[i][j] = (f32x4){0.f, 0.f, 0.f, 0.f};

#define PSTAGE_A(tt, bb) do {                                                 \
    const u16* s_ = Asrc + (size_t)(tt) * 64;                                 \
    _Pragma("unroll")                                                         \
    for (int j_ = 0; j_ < 4; ++j_)                                            \
      ASYNC16(s_ + (size_t)(wv + 8 * j_) * 8192,                              \
              smem + (bb) * 32768 + (wv + 8 * j_) * 1024);                    \
  } while (0)
#define PSTAGE_B(tt, bb) do {                                                 \
    const u16* s_ = Bsrc + (size_t)(tt) * 64;                                 \
    _Pragma("unroll")                                                         \
    for (int j_ = 0; j_ < 2; ++j_)                                            \
      ASYNC16(s_ + (size_t)(wv + 8 * j_) * 8192,                              \
              smem + 98304 + (bb) * 16384 + (wv + 8 * j_) * 1024);            \
  } while (0)

  // prologue: stage tiles 0 and 1
  PSTAGE_A(0, 0); PSTAGE_B(0, 0);
  PSTAGE_A(1, 1); PSTAGE_B(1, 1);
  asm volatile("s_waitcnt vmcnt(6)" ::: "memory");   // tile 0 landed
  __builtin_amdgcn_s_barrier();
  __builtin_amdgcn_sched_barrier(0);

  int cur = 0;
  for (int t = 0; t < 16; ++t) {
    const char* Ab = smem + cur * 32768;
    const char* Bb = smem + 98304 + cur * 16384;
    const int nb = (cur + 2 >= 3) ? cur - 1 : cur + 2;
    s16x8 aR[4][2], bR[4][2];

    // ---- phase A: stage t+2 (A part), read A+B(lo) frags, MFMA fn0-1 ------
    if (t < 14) PSTAGE_A(t + 2, nb);
#pragma unroll
    for (int fm = 0; fm < 4; ++fm) {
      aR[fm][0] = *(const s16x8*)(Ab + arow + fm * 2048 + sw0);
      aR[fm][1] = *(const s16x8*)(Ab + arow + fm * 2048 + sw1);
    }
#pragma unroll
    for (int fn = 0; fn < 2; ++fn) {
      bR[fn][0] = *(const s16x8*)(Bb + brow + fn * 2048 + sw0);
      bR[fn][1] = *(const s16x8*)(Bb + brow + fn * 2048 + sw1);
    }
    if (t < 14) PSTAGE_B(t + 2, nb);
    asm volatile("s_waitcnt lgkmcnt(0)" ::: "memory");
    __builtin_amdgcn_sched_barrier(0);
    __builtin_amdgcn_s_setprio(1);
#pragma unroll
    for (int fm = 0; fm < 4; ++fm)
#pragma unroll
      for (int fn = 0; fn < 2; ++fn) {
        acc[fm][fn] = __builtin_amdgcn_mfma_f32_16x16x32_bf16(
            aR[fm][0], bR[fn][0], acc[fm][fn], 0, 0, 0);
        acc[fm][fn] = __builtin_amdgcn_mfma_f32_16x16x32_bf16(
            aR[fm][1], bR[fn][1], acc[fm][fn], 0, 0, 0);
      }
    __builtin_amdgcn_s_setprio(0);
    __builtin_amdgcn_s_barrier();
    __builtin_amdgcn_sched_barrier(0);

    // ---- phase B: read B(hi) frags, MFMA fn2-3 ----------------------------
#pragma unroll
    for (int fn = 2; fn < 4; ++fn) {
      bR[fn][0] = *(const s16x8*)(Bb + brow + fn * 2048 + sw0);
      bR[fn][1] = *(const s16x8*)(Bb + brow + fn * 2048 + sw1);
    }
    asm volatile("s_waitcnt lgkmcnt(0)" ::: "memory");
    __builtin_amdgcn_sched_barrier(0);
    __builtin_amdgcn_s_setprio(1);
#pragma unroll
    for (int fm = 0; fm < 4; ++fm)
#pragma unroll
      for (int fn = 2; fn < 4; ++fn) {
        acc[fm][fn] = __builtin_amdgcn_mfma_f32_16x16x32_bf16(
            aR[fm][0], bR[fn][0], acc[fm][fn], 0, 0, 0);
        acc[fm][fn] = __builtin_amdgcn_mfma_f32_16x16x32_bf16(
            aR[fm][1], bR[fn][1], acc[fm][fn], 0, 0, 0);
      }
    __builtin_amdgcn_s_setprio(0);
    // counted drain: tile t+1's 6 loads landed; t+2's 6 stay in flight
    if (t < 14) asm volatile("s_waitcnt vmcnt(6)" ::: "memory");
    else        asm volatile("s_waitcnt vmcnt(0)" ::: "memory");
    __builtin_amdgcn_s_barrier();
    __builtin_amdgcn_sched_barrier(0);
    cur = (cur + 1 >= 3) ? 0 : cur + 1;
  }
#undef PSTAGE_A
#undef PSTAGE_B

  // epilogue
  const int crow = l >> 4, ccol = l & 15;
#pragma unroll
  for (int fm = 0; fm < 4; ++fm)
#pragma unroll
    for (int fn = 0; fn < 4; ++fn) {
      size_t rb = (size_t)(row0 + wr + fm * 16 + crow * 4);
      int col = col0 + wc + fn * 16 + ccol;
      if (OUTBF) {
        u16* C = (u16*)Cv;
#pragma unroll
        for (int r = 0; r < 4; ++r)
          C[(rb + r) * ldc + col] = f2bf(acc[fm][fn][r]);
      } else {
        float* C = (float*)Cv;
#pragma unroll
        for (int r = 0; r < 4; ++r)
          C[(rb + r) * ldc + col] = acc[fm][fn][r];
      }
    }
}

// ---------- deltas = q2view[8192][1280] @ dwbf^T + db, MFMA 64x64 tiles -----
// q2 flat element i lives at proj[(i>>10)*5120 + (i&1023)]
__global__ __launch_bounds__(256) void delta_mfma(
    const u16* __restrict__ proj, const u16* __restrict__ dwbf,
    const float* __restrict__ db, float* __restrict__ deltas)
{
  __shared__ __align__(16) u16 As[64 * 32];
  __shared__ __align__(16) u16 Bs[64 * 32];
  const int tid  = threadIdx.x;
  const int lane = tid & 63;
  const int w    = tid >> 6;
  const int row0 = blockIdx.x * 64;
  const int wr   = w * 16;
  const int lrow = lane & 15;
  const int lk   = lane >> 4;

  f32x4 acc[4];
#pragma unroll
  for (int j = 0; j < 4; ++j) acc[j] = (f32x4){0.f, 0.f, 0.f, 0.f};

  const size_t lin0 = (size_t)(row0 + (tid >> 2)) * 1280 + (tid & 3) * 8;
  const u16* Bg = dwbf + (size_t)(tid >> 2) * 1280 + (tid & 3) * 8;
  char* AsB = (char*)As;  char* BsB = (char*)Bs;
  char* aL = AsB + w * 1024;
  char* bL = BsB + w * 1024;

  const int aoff = (wr + lrow) * 64 + lk * 16;
  int boff[4];
#pragma unroll
  for (int f = 0; f < 4; ++f) boff[f] = (f * 16 + lrow) * 64 + lk * 16;

  for (int k0 = 0; k0 < 1280; k0 += 32) {
    if (k0) __syncthreads();
    size_t lin = lin0 + k0;
    ASYNC16(proj + (lin >> 10) * 5120 + (lin & 1023), aL);
    ASYNC16(Bg + k0, bL);
    asm volatile("s_waitcnt vmcnt(0)" ::: "memory");
    __syncthreads();

    s16x8 af = *(const s16x8*)(AsB + aoff);
#pragma unroll
    for (int fn = 0; fn < 4; ++fn) {
      s16x8 bfr = *(const s16x8*)(BsB + boff[fn]);
      acc[fn] = __builtin_amdgcn_mfma_f32_16x16x32_bf16(af, bfr, acc[fn], 0, 0, 0);
    }
  }

  const int crow = lane >> 4;
  const int ccol = lane & 15;
#pragma unroll
  for (int fn = 0; fn < 4; ++fn) {
    int col = fn * 16 + ccol;
    if (col < 60) {
      float d = db[col];
      size_t rb = (size_t)(row0 + wr + crow * 4);
#pragma unroll
      for (int r = 0; r < 4; ++r)
        deltas[(rb + r) * 60 + col] = acc[fn][r] + d;
    }
  }
}

// ---------- coords: pd = ref + deltas ; L2-normalize over the hi axis -------
__global__ void coords_kernel(const float* __restrict__ deltas,
                              float* __restrict__ vgx, float* __restrict__ vgy)
{
  int g = blockIdx.x * 256 + threadIdx.x;
  if (g >= 32 * 16 * 10 * 3) return;
  int kk = g % 3, tmp = g / 3;
  int s = tmp % 10; tmp /= 10;
  int wi = tmp % 16; int bnm = tmp / 16;
  float gxr = wi * (1.0f / 15.0f);
  float px[16], py[16];
  float sx = 0.f, sy = 0.f;
#pragma unroll
  for (int hi = 0; hi < 16; ++hi) {
    size_t base = ((size_t)((bnm * 16 + hi) * 16 + wi)) * 60 + (s * 3 + kk) * 2;
    float x = gxr + deltas[base];
    float y = hi * (1.0f / 15.0f) + deltas[base + 1];
    px[hi] = x; py[hi] = y;
    sx += x * x; sy += y * y;
  }
  float rx = 1.0f / fmaxf(sqrtf(sx), 1e-12f);
  float ry = 1.0f / fmaxf(sqrtf(sy), 1e-12f);
#pragma unroll
  for (int hi = 0; hi < 16; ++hi) {
    size_t o = ((size_t)((bnm * 16 + hi) * 16 + wi) * 10 + s) * 3 + kk;
    vgx[o] = px[hi] * rx;
    vgy[o] = py[hi] * ry;
  }
}

// ---------- MFMA attention: sample K (bilinear) + qk + softmax + PV ---------
// one block per (m,b); 4 waves. All operands from proj:
//   q2 flat i -> proj[(i>>10)*5120 + (i&1023)]
//   kp[n][c]  -> proj[n*5120 + 1024 + c]
//   vp[n][c]  -> proj[n*5120 + 2048 + c]
__global__ __launch_bounds__(256) void attn_mfma(
    const u16* __restrict__ proj, const float* __restrict__ vgx,
    const float* __restrict__ vgy, u16* __restrict__ headf,
    float* __restrict__ attn0)
{
  const int bid = blockIdx.x;
  const int m = bid >> 10, b = bid & 1023;
  const int tid = threadIdx.x;
  const int lane = tid & 63;
  const int w = tid >> 6;

  __shared__ __align__(16) u16 ksb[32][136];   // sampled K rows, bf16
  __shared__ __align__(16) u16 vt[128][32];    // V^T, col-swizzled t^8(v&3)
  __shared__ __align__(16) u16 pl[16][40];     // P bf16 (A-frag layout)
  __shared__ float wst[30][4];
  __shared__ int   cst[30][4];

  // preload Q A-frags (wave 0 only); rows>=10 read ws garbage (ok)
  s16x8 aq[4];
  if (w == 0) {
    size_t linb = (size_t)bid * 1280 + (size_t)(lane & 15) * 128 + (lane >> 4) * 8;
#pragma unroll
    for (int kk = 0; kk < 4; ++kk) {
      size_t lin = linb + kk * 32;
      aq[kk] = *(const s16x8*)(proj + (lin >> 10) * 5120 + (lin & 1023));
    }
  }

  // bilinear coefficients (t = kk*10 + sk)
  if (tid < 30) {
    int t = tid, kk = t / 10, sk = t % 10;
    size_t ci = ((size_t)bid * 10 + sk) * 3 + kk;
    float gx = vgx[ci], gy = vgy[ci];
    float ix = (gx + 1.0f) * 8.0f - 0.5f;
    float iy = (gy + 1.0f) * 8.0f - 0.5f;
    float x0f = floorf(ix), y0f = floorf(iy);
    float wx1 = ix - x0f, wx0 = 1.0f - wx1;
    float wy1 = iy - y0f, wy0 = 1.0f - wy1;
    float x1f = x0f + 1.0f, y1f = y0f + 1.0f;
    bool vx0 = (x0f >= 0.f) && (x0f <= 15.f);
    bool vx1 = (x1f >= 0.f) && (x1f <= 15.f);
    bool vy0 = (y0f >= 0.f) && (y0f <= 15.f);
    bool vy1 = (y1f >= 0.f) && (y1f <= 15.f);
    int x0 = min(max((int)x0f, 0), 15);
    int x1 = min(max((int)x1f, 0), 15);
    int y0 = min(max((int)y0f, 0), 15);
    int y1 = min(max((int)y1f, 0), 15);
    wst[t][0] = wx0 * wy0 * ((vx0 && vy0) ? 1.f : 0.f);
    wst[t][1] = wx1 * wy0 * ((vx1 && vy0) ? 1.f : 0.f);
    wst[t][2] = wx0 * wy1 * ((vx0 && vy1) ? 1.f : 0.f);
    wst[t][3] = wx1 * wy1 * ((vx1 && vy1) ? 1.f : 0.f);
    cst[t][0] = x0; cst[t][1] = x1; cst[t][2] = y0; cst[t][3] = y1;
  }
  __syncthreads();

  // stage V^T (swizzled): 512 items, t = i&31 (t>=30 -> zeros), c = i>>5
  for (int i = tid; i < 512; i += 256) {
    int t = i & 31, c = i >> 5;
    u16x8 v = (u16x8){0, 0, 0, 0, 0, 0, 0, 0};
    if (t < 30) {
      int sv = t / 3, cv = t - sv * 3;
      v = *(const u16x8*)(proj + ((size_t)(b * 10 + sv)) * 5120 + 2048 +
                          m * 384 + cv * 128 + c * 8);
    }
#pragma unroll
    for (int r = 0; r < 8; ++r)
      vt[8 * c + r][t ^ (8 * (r & 3))] = v[r];
  }

  // bilinear-sample K rows -> ksb bf16: 480 items (t 0..29, c 0..15)
  {
    int pb = (b >> 8) << 8;
    for (int i = tid; i < 480; i += 256) {
      int t = i >> 4, c = i & 15;
      int sk = t % 10;
      int x0 = cst[t][0], x1 = cst[t][1], y0 = cst[t][2], y1 = cst[t][3];
      float w00 = wst[t][0], w10 = wst[t][1], w01 = wst[t][2], w11 = wst[t][3];
      size_t colo = 1024 + (size_t)m * 128 + c * 8;
      const u16x8 f00 = *(const u16x8*)&proj[((size_t)((pb + y0 * 16 + x0) * 10 + sk)) * 5120 + colo];
      const u16x8 f10 = *(const u16x8*)&proj[((size_t)((pb + y0 * 16 + x1) * 10 + sk)) * 5120 + colo];
      const u16x8 f01 = *(const u16x8*)&proj[((size_t)((pb + y1 * 16 + x0) * 10 + sk)) * 5120 + colo];
      const u16x8 f11 = *(const u16x8*)&proj[((size_t)((pb + y1 * 16 + x1) * 10 + sk)) * 5120 + colo];
      u16x8 o;
#pragma unroll
      for (int r = 0; r < 8; ++r) {
        float acc = w00 * bf2f(f00[r]) + w10 * bf2f(f10[r]) +
                    w01 * bf2f(f01[r]) + w11 * bf2f(f11[r]);
        o[r] = f2bf(acc);
      }
      *(u16x8*)&ksb[t][c * 8] = o;
    }
  }
  __syncthreads();

  // wave 0: qk MFMA (M=16,N=32,K=128) + in-register softmax + P->LDS
  if (w == 0) {
    f32x4 dq[2];
    dq[0] = (f32x4){0.f, 0.f, 0.f, 0.f};
    dq[1] = (f32x4){0.f, 0.f, 0.f, 0.f};
    const int lr = lane & 15, g = lane >> 4;
#pragma unroll
    for (int kk = 0; kk < 4; ++kk) {
      s16x8 b0 = *(const s16x8*)&ksb[lr][g * 8 + kk * 32];
      s16x8 b1 = *(const s16x8*)&ksb[16 + lr][g * 8 + kk * 32];
      dq[0] = __builtin_amdgcn_mfma_f32_16x16x32_bf16(aq[kk], b0, dq[0], 0, 0, 0);
      dq[1] = __builtin_amdgcn_mfma_f32_16x16x32_bf16(aq[kk], b1, dq[1], 0, 0, 0);
    }
    // lane holds D[s = g*4+r][t = lr + 16*f]; softmax over t (30 valid)
    float p[2][4];
#pragma unroll
    for (int f = 0; f < 2; ++f) {
      int t = lr + 16 * f;
#pragma unroll
      for (int r = 0; r < 4; ++r) {
        float v = dq[f][r] * 0.08838834764831845f;
        p[f][r] = (t < 30) ? v : -1e30f;
      }
    }
#pragma unroll
    for (int r = 0; r < 4; ++r) {
      float mx = fmaxf(p[0][r], p[1][r]);
#pragma unroll
      for (int msk = 1; msk <= 8; msk <<= 1) mx = fmaxf(mx, __shfl_xor(mx, msk));
      float e0 = __expf(p[0][r] - mx);
      float e1 = __expf(p[1][r] - mx);
      float sm = e0 + e1;
#pragma unroll
      for (int msk = 1; msk <= 8; msk <<= 1) sm += __shfl_xor(sm, msk);
      float inv = 1.0f / sm;
      p[0][r] = e0 * inv;
      p[1][r] = e1 * inv;
    }
    if (g == 0) {
      attn0[(size_t)bid * 30 + lr] = p[0][0];
      if (lr < 14) attn0[(size_t)bid * 30 + 16 + lr] = p[1][0];
    }
#pragma unroll
    for (int f = 0; f < 2; ++f)
#pragma unroll
      for (int r = 0; r < 4; ++r)
        pl[g * 4 + r][lr + 16 * f] = f2bf(p[f][r]);
  }
  __syncthreads();

  // PV: all waves; frags fv = 2w, 2w+1 (v0 = fv*16); K=32 one step
  const int lr = lane & 15, g = lane >> 4;
  s16x8 pa = *(const s16x8*)&pl[lr][g * 8];
#pragma unroll
  for (int qf = 0; qf < 2; ++qf) {
    int fv = w * 2 + qf;
    int v = fv * 16 + lr;
    s16x8 bv = *(const s16x8*)&vt[v][8 * (g ^ (v & 3))];
    f32x4 acc = (f32x4){0.f, 0.f, 0.f, 0.f};
    acc = __builtin_amdgcn_mfma_f32_16x16x32_bf16(pa, bv, acc, 0, 0, 0);
#pragma unroll
    for (int r = 0; r < 4; ++r) {
      int s = g * 4 + r;
      if (s < 10)
        headf[((size_t)(b * 10 + s)) * 1024 + m * 128 + v] = f2bf(acc[r]);
    }
  }
}

// ---------- attn_map[b][t] = mean_m attn0[m][b][t] --------------------------
__global__ void attnmap_kernel(const float* __restrict__ attn0, float* __restrict__ outa)
{
  int i = blockIdx.x * 256 + threadIdx.x;
  if (i >= 30720) return;
  int b = i / 30, t = i % 30;
  float s = 0.f;
  for (int mm = 0; mm < 8; ++mm) s += attn0[((size_t)mm * 1024 + b) * 30 + t];
  outa[i] = 0.125f * s;
}

// ---------------------------------------------------------------------------
extern "C" void kernel_launch(void* const* d_in, const int* in_sizes, int n_in,
                              void* d_out, int out_size, void* d_ws, size_t ws_size,
                              hipStream_t stream)
{
  const float* q  = (const float*)d_in[0];
  const float* Wq = (const float*)d_in[1];
  const float* Wk = (const float*)d_in[2];
  const float* Wv = (const float*)d_in[3];
  const float* Wo = (const float*)d_in[4];
  const float* dw = (const float*)d_in[5];
  const float* db = (const float*)d_in[6];
  float* out = (float*)d_out;
  float* attn_out = out + 10485760;

  // workspace layout (bytes): total ~165 MB
  char* p = (char*)d_ws;
  u16*   Abf   = (u16*)p;   p += 20971520;    // [10240][1024] bf16
  u16*   Wcat  = (u16*)p;   p += 12582912;    // [6144][1024] bf16 (B^T fused)
  u16*   proj  = (u16*)p;   p += 104857600;   // [10240][5120] bf16 (q2|kp|vp)
  u16*   headf = (u16*)p;   p += 20971520;    // [10240][1024] bf16
  u16*   dwbf  = (u16*)p;   p += 163840;      // [64][1280] bf16
  float* dels  = (float*)p; p += 1966080;     // [8192][60]
  float* vgxp  = (float*)p; p += 983040;
  float* vgyp  = (float*)p; p += 983040;
  float* attn0 = (float*)p; p += 983040;

  conv_a<<<dim3(5120), dim3(256), 0, stream>>>(q, Abf, 1310720);
  conv_w<<<dim3(3072), dim3(256), 0, stream>>>(Wq, Wk, Wv, Wo, Wcat);
  conv_dw<<<dim3(40), dim3(256), 0, stream>>>(dw, dwbf);

  // fused projections: proj = Abf @ Wcat[0:5120]^T  (107 GFLOP, one dispatch)
  gemm_pipe<1><<<dim3(40, 40), dim3(512), 147456, stream>>>(Abf, Wcat, proj, 5120);

  delta_mfma<<<dim3(128), dim3(256), 0, stream>>>(proj, dwbf, db, dels);
  coords_kernel<<<dim3(60), dim3(256), 0, stream>>>(dels, vgxp, vgyp);
  attn_mfma<<<dim3(8192), dim3(256), 0, stream>>>(proj, vgxp, vgyp, headf, attn0);
  attnmap_kernel<<<dim3(120), dim3(256), 0, stream>>>(attn0, attn_out);

  // out = headf @ Wo^T (Wcat rows 5120..6143)
  gemm_pipe<0><<<dim3(40, 8), dim3(512), 147456, stream>>>(
      headf, Wcat + (size_t)5120 * 1024, out, 1024);
}